// Round 10
// baseline (588.655 us; speedup 1.0000x reference)
//
#include <hip/hip_runtime.h>
#include <hip/hip_bf16.h>
#include <math.h>

#define NN 32768
#define EE 524288
#define FF 32
#define HH 512
#define GG 64
#define CC 10

typedef __attribute__((ext_vector_type(8))) short short8;
typedef __attribute__((ext_vector_type(4))) float floatx4;
typedef __attribute__((ext_vector_type(4))) unsigned int uintx4;

__device__ __forceinline__ float bf16_to_f32(unsigned short u) {
    union { unsigned int u; float f; } v;
    v.u = ((unsigned int)u) << 16;
    return v.f;
}
__device__ __forceinline__ unsigned short f32_to_bf16(float f) {
    union { float f; unsigned int u; } v;
    v.f = f;
    unsigned int u = v.u;
    u += 0x7FFFu + ((u >> 16) & 1u);   // round-to-nearest-even
    return (unsigned short)(u >> 16);
}
// tanh(x) = 1 - 2/(1+e^{2x});  exact at +-inf, err far below bf16 grid
__device__ __forceinline__ float fast_tanh(float x) {
    float e = __expf(2.0f * x);
    return 1.0f - 2.0f * __builtin_amdgcn_rcpf(e + 1.0f);
}

// ---------------------------------------------------------------------------
// Merged prep: LDS-tiled weight transpose + X0 cast + counts/degHist zero.
// blocks [0,8): WT0; [8,520): WTs; [520,4616): X0 cast; [4616,4649): zero
// (counts NN ints + degHist 256 ints, contiguous).
// ---------------------------------------------------------------------------
__global__ __launch_bounds__(256) void prep_all_kernel(const float* __restrict__ wr0, const float* __restrict__ wl0,
                                unsigned short* __restrict__ WT0,
                                const float* __restrict__ wroot, const float* __restrict__ wrel,
                                unsigned short* __restrict__ WTs,
                                const float* __restrict__ x, unsigned short* __restrict__ X0,
                                int* __restrict__ counts) {
    const int b = blockIdx.x;
    const int tid = threadIdx.x;
    if (b < 520) {
        __shared__ unsigned short tile[64][65];
        const int ty = tid >> 6, tx = tid & 63;
        if (b < 8) {
            const int n0 = b * 64;
#pragma unroll
            for (int q = 0; q < 16; ++q) {
                const int k = ty * 16 + q;
                const float v = (k < 32) ? wr0[k * 512 + n0 + tx]
                                         : wl0[(k - 32) * 512 + n0 + tx];
                tile[k][tx] = f32_to_bf16(v);
            }
            __syncthreads();
#pragma unroll
            for (int q = 0; q < 16; ++q) {
                const int n = n0 + ty * 16 + q;
                WT0[n * 64 + tx] = tile[tx][ty * 16 + q];
            }
        } else {
            const int bb = b - 8;          // 0..511
            const int l = bb >> 7;         // layer
            const int r = bb & 127;        // 16 ktile x 8 ntile
            const int k0 = (r >> 3) * 64;  // multiple of 64 -> never straddles 512
            const int n0 = (r & 7) * 64;
            const float* Wl = (k0 < 512) ? wroot + (size_t)l * 262144
                                         : wrel + (size_t)l * 262144;
            const int kb = (k0 < 512) ? k0 : k0 - 512;
#pragma unroll
            for (int q = 0; q < 16; ++q) {
                const int kk = ty * 16 + q;
                tile[kk][tx] = f32_to_bf16(Wl[(size_t)(kb + kk) * 512 + n0 + tx]);
            }
            __syncthreads();
#pragma unroll
            for (int q = 0; q < 16; ++q) {
                const int n = n0 + ty * 16 + q;
                WTs[(size_t)l * 524288 + (size_t)n * 1024 + k0 + tx] = tile[tx][ty * 16 + q];
            }
        }
    } else if (b < 4616) {
        const int t = (b - 520) * 256 + tid; // NN*32
        const int i = t >> 5, c = t & 31;
        X0[(size_t)i * 64 + c] = f32_to_bf16(x[t]);
    } else {
        const int t4 = (b - 4616) * 256 + tid;   // counts+degHist = (NN+256)/4 = 8256 int4
        if (t4 < 8256) {
            int4 z; z.x = 0; z.y = 0; z.z = 0; z.w = 0;
            ((int4*)counts)[t4] = z;
        }
    }
}

// ---------------------------------------------------------------------------
// hist: per-dst degree counts (counts zeroed by prep).
// ---------------------------------------------------------------------------
__global__ void hist_kernel(const int* __restrict__ dst, int* __restrict__ counts) {
    int e = blockIdx.x * blockDim.x + threadIdx.x;
    if (e < EE) atomicAdd(&counts[dst[e]], 1);
}

// degree histogram (bin = 255-deg -> descending sort), LDS pre-aggregated,
// 128 blocks.
__global__ __launch_bounds__(256) void deg_hist_kernel(const int* __restrict__ counts,
                                                       int* __restrict__ degHist) {
    __shared__ int lh[256];
    lh[threadIdx.x] = 0;
    __syncthreads();
    int i = blockIdx.x * 256 + threadIdx.x;
    int d = counts[i]; if (d > 255) d = 255;
    atomicAdd(&lh[255 - d], 1);
    __syncthreads();
    int v = lh[threadIdx.x];
    if (v) atomicAdd(&degHist[threadIdx.x], v);
}
__global__ __launch_bounds__(256) void deg_scan_kernel(const int* __restrict__ degHist,
                                                       int* __restrict__ degCursor) {
    __shared__ int sh[256];
    const int t = threadIdx.x;
    int own = degHist[t];
    sh[t] = own;
    __syncthreads();
    for (int off = 1; off < 256; off <<= 1) {
        int v = (t >= off) ? sh[t - off] : 0;
        __syncthreads();
        sh[t] += v;
        __syncthreads();
    }
    degCursor[t] = sh[t] - own;   // exclusive prefix
}
// scatter nodes into descending-degree order; also writes iperm for the
// direct permuted edge scatter.
__global__ __launch_bounds__(256) void deg_scatter_kernel(const int* __restrict__ counts,
                                                          int* __restrict__ degCursor,
                                                          int* __restrict__ perm,
                                                          int* __restrict__ pDeg,
                                                          int* __restrict__ iperm) {
    __shared__ int lh[256];
    __shared__ int base[256];
    lh[threadIdx.x] = 0;
    __syncthreads();
    int i = blockIdx.x * 256 + threadIdx.x;
    int dtrue = counts[i];
    int d = dtrue > 255 ? 255 : dtrue;
    int bin = 255 - d;
    int lr = atomicAdd(&lh[bin], 1);      // local rank within (block, bin)
    __syncthreads();
    int c = lh[threadIdx.x];
    if (c) base[threadIdx.x] = atomicAdd(&degCursor[threadIdx.x], c);
    __syncthreads();
    int p = base[bin] + lr;
    perm[p] = i;
    pDeg[p] = dtrue;
    iperm[i] = p;
}
// scan pDeg (permuted order) -> pRowStart, pCursor (1024thr x 32/thread)
__global__ __launch_bounds__(1024) void scan_kernel(const int* __restrict__ pDeg,
                                                    int* __restrict__ pRowStart,
                                                    int* __restrict__ pCursor) {
    __shared__ int part[1024];
    const int t = threadIdx.x;
    const int base = t * 32;
    int local[32];
    const int4* cp = (const int4*)(pDeg + base);
    int s = 0;
#pragma unroll
    for (int ii = 0; ii < 8; ++ii) {
        int4 v = cp[ii];
        local[ii * 4 + 0] = v.x; local[ii * 4 + 1] = v.y;
        local[ii * 4 + 2] = v.z; local[ii * 4 + 3] = v.w;
        s += v.x + v.y + v.z + v.w;
    }
    part[t] = s;
    __syncthreads();
    for (int off = 1; off < 1024; off <<= 1) {
        int v = (t >= off) ? part[t - off] : 0;
        __syncthreads();
        part[t] += v;
        __syncthreads();
    }
    int run = part[t] - s;
#pragma unroll
    for (int i = 0; i < 32; ++i) {
        pRowStart[base + i] = run;
        pCursor[base + i] = run;
        run += local[i];
    }
    if (t == 1023) pRowStart[NN] = run;
}

// ---------------------------------------------------------------------------
// scatter: edges go DIRECTLY into permuted CSR (no ssrc / edge_copy).
// ---------------------------------------------------------------------------
__global__ void scatter_kernel(const int* __restrict__ src, const int* __restrict__ dst,
                               const int* __restrict__ iperm,
                               int* __restrict__ pCursor, int* __restrict__ pssrc) {
    int e = blockIdx.x * blockDim.x + threadIdx.x;
    if (e < EE) {
        int p = iperm[dst[e]];
        int q = atomicAdd(&pCursor[p], 1);
        pssrc[q] = src[e];
    }
}

// ---------------------------------------------------------------------------
__device__ __forceinline__ void acc8(float* a, uint4 d) {
    a[0] += bf16_to_f32((unsigned short)(d.x & 0xFFFFu));
    a[1] += bf16_to_f32((unsigned short)(d.x >> 16));
    a[2] += bf16_to_f32((unsigned short)(d.y & 0xFFFFu));
    a[3] += bf16_to_f32((unsigned short)(d.y >> 16));
    a[4] += bf16_to_f32((unsigned short)(d.z & 0xFFFFu));
    a[5] += bf16_to_f32((unsigned short)(d.z >> 16));
    a[6] += bf16_to_f32((unsigned short)(d.w & 0xFFFFu));
    a[7] += bf16_to_f32((unsigned short)(d.w >> 16));
}
__device__ __forceinline__ void acc8v(float* a, uintx4 d) {
    a[0] += bf16_to_f32((unsigned short)(d[0] & 0xFFFFu));
    a[1] += bf16_to_f32((unsigned short)(d[0] >> 16));
    a[2] += bf16_to_f32((unsigned short)(d[1] & 0xFFFFu));
    a[3] += bf16_to_f32((unsigned short)(d[1] >> 16));
    a[4] += bf16_to_f32((unsigned short)(d[2] & 0xFFFFu));
    a[5] += bf16_to_f32((unsigned short)(d[2] >> 16));
    a[6] += bf16_to_f32((unsigned short)(d[3] & 0xFFFFu));
    a[7] += bf16_to_f32((unsigned short)(d[3] >> 16));
}

// Layer-0 agg (cols=32), permuted CSR: 16 nodes/wave x 4 lanes/node.
__global__ __launch_bounds__(256) void agg_kernel(const unsigned short* __restrict__ Xh,
                                                  unsigned short* __restrict__ Xagg,
                                                  const int* __restrict__ pRowStart,
                                                  const int* __restrict__ pssrc,
                                                  const int* __restrict__ perm) {
    const int p = blockIdx.x * 64 + (threadIdx.x >> 2);
    const int lc = threadIdx.x & 3;
    const int node = perm[p];
    const int s = pRowStart[p];
    const int e = pRowStart[p + 1];
    float a[8] = {0.f, 0.f, 0.f, 0.f, 0.f, 0.f, 0.f, 0.f};
    const unsigned short* base = Xh + lc * 8;
    int i = s;
    for (; i + 4 <= e; i += 4) {
        int j0 = pssrc[i], j1 = pssrc[i + 1], j2 = pssrc[i + 2], j3 = pssrc[i + 3];
        uint4 d0 = *(const uint4*)(base + (size_t)j0 * 64);
        uint4 d1 = *(const uint4*)(base + (size_t)j1 * 64);
        uint4 d2 = *(const uint4*)(base + (size_t)j2 * 64);
        uint4 d3 = *(const uint4*)(base + (size_t)j3 * 64);
        acc8(a, d0); acc8(a, d1); acc8(a, d2); acc8(a, d3);
    }
    for (; i < e; ++i) {
        int j = pssrc[i];
        uint4 d = *(const uint4*)(base + (size_t)j * 64);
        acc8(a, d);
    }
    unsigned short* out = Xagg + (size_t)node * 64 + lc * 8;
#pragma unroll
    for (int c = 0; c < 8; ++c) out[c] = f32_to_bf16(a[c]);
}

// ---------------------------------------------------------------------------
// Column-sliced XCD-affine agg v6 (proven config: 47.2us).
// ---------------------------------------------------------------------------
#define GLOAD(dreg, voff) \
    asm volatile("buffer_load_dwordx4 %0, %1, %2, 0 offen" \
                 : "=v"(dreg) : "v"(voff), "s"(srsrc))

__global__ __launch_bounds__(256, 3) void agg_slice_kernel(const unsigned short* __restrict__ Xh,
                                                           unsigned short* __restrict__ Xagg,
                                                           const int* __restrict__ pRowStart,
                                                           const int* __restrict__ pssrc,
                                                           const int* __restrict__ perm) {
    const int slice = blockIdx.x & 7;
    const int pair = blockIdx.x >> 3;          // 0..511
    const int wv = threadIdx.x >> 6;
    const int lane = threadIdx.x & 63;
    const int ln = lane >> 3;
    const int lc = lane & 7;
    const int colOff = slice * 64 + lc * 8;
    const unsigned short* base = Xh + colOff;     // tail path (compiler loads)
    uintx4 srsrc;
    {
        union { const unsigned short* p; unsigned int u[2]; } ba;
        ba.p = Xh + slice * 64;
        srsrc[0] = ba.u[0];
        srsrc[1] = ba.u[1] & 0xFFFFu;   // stride = 0
        srsrc[2] = 0xFFFFFFFFu;         // num_records: bounds check disabled
        srsrc[3] = 0x00020000u;         // raw untyped dword
    }
    const unsigned int lcoff = (unsigned int)(lc << 4);
#pragma unroll
    for (int half = 0; half < 2; ++half) {
        const int nb = half ? (1023 - pair) : pair;
        const int p = nb * 32 + wv * 8 + ln;
        const int node = perm[p];
        const int s = pRowStart[p];
        const int e = pRowStart[p + 1];
        float a[8] = {0.f, 0.f, 0.f, 0.f, 0.f, 0.f, 0.f, 0.f};
        int i = s;
        for (; i + 16 <= e; i += 16) {
            unsigned int vo[16];
#pragma unroll
            for (int u = 0; u < 16; ++u)
                vo[u] = (((unsigned int)pssrc[i + u]) << 11) | lcoff;
            uintx4 d0, d1, d2, d3, d4, d5, d6, d7, d8, d9, d10, d11, d12, d13, d14, d15;
            __builtin_amdgcn_sched_barrier(0);
            GLOAD(d0, vo[0]);   GLOAD(d1, vo[1]);   GLOAD(d2, vo[2]);   GLOAD(d3, vo[3]);
            GLOAD(d4, vo[4]);   GLOAD(d5, vo[5]);   GLOAD(d6, vo[6]);   GLOAD(d7, vo[7]);
            GLOAD(d8, vo[8]);   GLOAD(d9, vo[9]);   GLOAD(d10, vo[10]); GLOAD(d11, vo[11]);
            GLOAD(d12, vo[12]); GLOAD(d13, vo[13]); GLOAD(d14, vo[14]); GLOAD(d15, vo[15]);
            asm volatile("s_waitcnt vmcnt(8)" ::: "memory");
            __builtin_amdgcn_sched_barrier(0);
            acc8v(a, d0); acc8v(a, d1); acc8v(a, d2); acc8v(a, d3);
            acc8v(a, d4); acc8v(a, d5); acc8v(a, d6); acc8v(a, d7);
            asm volatile("s_waitcnt vmcnt(0)" ::: "memory");
            __builtin_amdgcn_sched_barrier(0);
            acc8v(a, d8);  acc8v(a, d9);  acc8v(a, d10); acc8v(a, d11);
            acc8v(a, d12); acc8v(a, d13); acc8v(a, d14); acc8v(a, d15);
        }
        if (e - i >= 8) {
            unsigned int vo[8];
#pragma unroll
            for (int u = 0; u < 8; ++u)
                vo[u] = (((unsigned int)pssrc[i + u]) << 11) | lcoff;
            uintx4 d0, d1, d2, d3, d4, d5, d6, d7;
            __builtin_amdgcn_sched_barrier(0);
            GLOAD(d0, vo[0]); GLOAD(d1, vo[1]); GLOAD(d2, vo[2]); GLOAD(d3, vo[3]);
            GLOAD(d4, vo[4]); GLOAD(d5, vo[5]); GLOAD(d6, vo[6]); GLOAD(d7, vo[7]);
            asm volatile("s_waitcnt vmcnt(4)" ::: "memory");
            __builtin_amdgcn_sched_barrier(0);
            acc8v(a, d0); acc8v(a, d1); acc8v(a, d2); acc8v(a, d3);
            asm volatile("s_waitcnt vmcnt(0)" ::: "memory");
            __builtin_amdgcn_sched_barrier(0);
            acc8v(a, d4); acc8v(a, d5); acc8v(a, d6); acc8v(a, d7);
            i += 8;
        }
        for (; i + 4 <= e; i += 4) {
            int j0 = pssrc[i], j1 = pssrc[i + 1], j2 = pssrc[i + 2], j3 = pssrc[i + 3];
            uint4 e0 = *(const uint4*)(base + (size_t)j0 * 1024);
            uint4 e1 = *(const uint4*)(base + (size_t)j1 * 1024);
            uint4 e2 = *(const uint4*)(base + (size_t)j2 * 1024);
            uint4 e3 = *(const uint4*)(base + (size_t)j3 * 1024);
            acc8(a, e0); acc8(a, e1); acc8(a, e2); acc8(a, e3);
        }
        for (; i < e; ++i) {
            int j = pssrc[i];
            uint4 d = *(const uint4*)(base + (size_t)j * 1024);
            acc8(a, d);
        }
        unsigned short* out = Xagg + (size_t)node * 1024 + colOff;
#pragma unroll
        for (int c = 0; c < 8; ++c) out[c] = f32_to_bf16(a[c]);
    }
}

// ---------------------------------------------------------------------------
// bf16 MFMA GEMM 128x128: BK=64, XOR-swizzled LDS. Grid dim3(M/128, N/128).
// A/B candidate (multi-block/CU: barrier stalls hidden by co-residents).
// ---------------------------------------------------------------------------
__global__ __launch_bounds__(256, 4) void gemm_bias_tanh(const unsigned short* __restrict__ Xin,
                                                         int ldin, int K,
                                                         const unsigned short* __restrict__ WT,
                                                         const float* __restrict__ bias,
                                                         unsigned short* __restrict__ Xout,
                                                         int ldout) {
    __shared__ __align__(16) unsigned short As[128 * 64];
    __shared__ __align__(16) unsigned short Bs[128 * 64];
    const int tid = threadIdx.x;
    const int lane = tid & 63;
    const int wave = tid >> 6;
    const int wm = wave >> 1, wn = wave & 1;
    const int bm = blockIdx.x, bn = blockIdx.y;

    floatx4 acc[4][4] = {};

    const int lrow = lane >> 3;
    const int schunk = (lane & 7) ^ (lrow & 7);
    const unsigned short* Abase = Xin + (size_t)(bm * 128) * ldin;
    const unsigned short* Bbase = WT + (size_t)(bn * 128) * K;
    const int m = lane & 15;
    const int quad = lane >> 4;

    for (int k0 = 0; k0 < K; k0 += 64) {
        __syncthreads();
#pragma unroll
        for (int q = 0; q < 4; ++q) {
            const int rr = q * 32 + wave * 8;
            const int row = rr + lrow;
            const unsigned short* sa = Abase + (size_t)row * ldin + (k0 + schunk * 8);
            const unsigned short* sb = Bbase + (size_t)row * K + (k0 + schunk * 8);
            __builtin_amdgcn_global_load_lds(
                (const __attribute__((address_space(1))) void*)sa,
                (__attribute__((address_space(3))) void*)(&As[rr * 64]), 16, 0, 0);
            __builtin_amdgcn_global_load_lds(
                (const __attribute__((address_space(1))) void*)sb,
                (__attribute__((address_space(3))) void*)(&Bs[rr * 64]), 16, 0, 0);
        }
        __syncthreads();
#pragma unroll
        for (int half = 0; half < 2; ++half) {
            short8 af[4], bfr[4];
#pragma unroll
            for (int t = 0; t < 4; ++t) {
                const int row = wm * 64 + t * 16 + m;
                const int chunk = (half * 4 + quad) ^ (row & 7);
                af[t] = *(const short8*)&As[row * 64 + chunk * 8];
            }
#pragma unroll
            for (int t = 0; t < 4; ++t) {
                const int row = wn * 64 + t * 16 + m;
                const int chunk = (half * 4 + quad) ^ (row & 7);
                bfr[t] = *(const short8*)&Bs[row * 64 + chunk * 8];
            }
#pragma unroll
            for (int mt = 0; mt < 4; ++mt)
#pragma unroll
                for (int nt = 0; nt < 4; ++nt)
                    acc[mt][nt] = __builtin_amdgcn_mfma_f32_16x16x32_bf16(af[mt], bfr[nt],
                                                                          acc[mt][nt], 0, 0, 0);
        }
    }

    const int row0 = bm * 128 + wm * 64;
    const int col0 = bn * 128 + wn * 64;
#pragma unroll
    for (int mt = 0; mt < 4; ++mt) {
#pragma unroll
        for (int nt = 0; nt < 4; ++nt) {
            const int col = col0 + nt * 16 + m;
            const float bv = bias[col];
#pragma unroll
            for (int r = 0; r < 4; ++r) {
                const int row = row0 + mt * 16 + quad * 4 + r;
                float v = fast_tanh(acc[mt][nt][r] + bv);
                Xout[(size_t)row * ldout + col] = f32_to_bf16(v);
            }
        }
    }
}

// ---------------------------------------------------------------------------
// 256x256 8-phase bf16 MFMA GEMM, v2 (race-fixed). A/B candidate
// (1 block/CU at 128KB LDS; R8 measured 62.5us/layer, MfmaUtil 20.8%).
// ---------------------------------------------------------------------------
__device__ __forceinline__ void stage_half(const unsigned short* __restrict__ gsrc0,
                                           int ldg, unsigned short* ldsHalf,
                                           int w, int lane) {
#pragma unroll
    for (int q = 0; q < 2; ++q) {
        const int rb = q * 64 + w * 8;                       // wave-uniform row block (8 rows)
        const unsigned short* src = gsrc0 + (size_t)(rb + (lane >> 3)) * ldg
                                    + ((lane & 7) ^ (lane >> 3)) * 8;   // pre-swizzled source
        __builtin_amdgcn_global_load_lds(
            (const __attribute__((address_space(1))) void*)src,
            (__attribute__((address_space(3))) void*)(ldsHalf + rb * 64), 16, 0, 0);
    }
}
// stage one 64-row quarter: 1 load/wave (8 waves x 8 rows)
__device__ __forceinline__ void stage_q(const unsigned short* __restrict__ gsrc0,
                                        int ldg, unsigned short* ldsQ,
                                        int w, int lane) {
    const unsigned short* src = gsrc0 + (size_t)(w * 8 + (lane >> 3)) * ldg
                                + ((lane & 7) ^ (lane >> 3)) * 8;
    __builtin_amdgcn_global_load_lds(
        (const __attribute__((address_space(1))) void*)src,
        (__attribute__((address_space(3))) void*)(ldsQ + (w * 8) * 64), 16, 0, 0);
}

__global__ __launch_bounds__(512, 2) void gemm256_bias_tanh(
    const unsigned short* __restrict__ Xin, int ldin, int K,
    const unsigned short* __restrict__ WT, const float* __restrict__ bias,
    unsigned short* __restrict__ Xout, int ldout) {
    __shared__ __align__(16) unsigned short As[2][256 * 64];   // 64KB
    __shared__ __align__(16) unsigned short Bs[2][256 * 64];   // 64KB
    const int tid = threadIdx.x;
    const int lane = tid & 63;
    const int w = tid >> 6;                 // 0..7
    const int wm = w >> 2, wn = w & 3;      // 2 x 4 wave grid
    const int m = lane & 15, quad = lane >> 4;
    const int id = (int)blockIdx.x;
    const int bm = (id & 7) * 16 + (id >> 4);
    const int bn = (id >> 3) & 1;
    const int NT = K >> 6;

    const unsigned short* Abase = Xin + (size_t)(bm * 256) * ldin;
    const unsigned short* Bbase = WT + (size_t)(bn * 256) * K;

    floatx4 acc[8][4] = {};

#define STG_AH(buf, h, kt_) stage_half(Abase + (size_t)((h) * 128) * ldin + (kt_) * 64, ldin, \
                                       &As[buf][(h) * 128 * 64], w, lane)
#define STG_BH(buf, h, kt_) stage_half(Bbase + (size_t)((h) * 128) * K + (kt_) * 64, K, \
                                       &Bs[buf][(h) * 128 * 64], w, lane)
#define STG_AQ(buf, qr, kt_) stage_q(Abase + (size_t)((qr) * 64) * ldin + (kt_) * 64, ldin, \
                                     &As[buf][(qr) * 64 * 64], w, lane)

    // prologue: tiles 0 and 1 (16 loads/wave; first 8 are exactly tile 0)
    STG_BH(0, 0, 0); STG_BH(0, 1, 0); STG_AH(0, 0, 0); STG_AH(0, 1, 0);
    STG_BH(1, 0, 1); STG_BH(1, 1, 1); STG_AH(1, 0, 1); STG_AH(1, 1, 1);
    asm volatile("s_waitcnt vmcnt(8)" ::: "memory");   // tile 0 fully landed
    __builtin_amdgcn_s_barrier();

    for (int kt = 0; kt < NT; ++kt) {
        const int cur = kt & 1;
        const unsigned short* Ac = &As[cur][0];
        const unsigned short* Bc = &Bs[cur][0];
        const bool pf = (kt + 2 < NT);
        short8 afr[8], bfr[8];

        // ---- phase 0: read B(all) + A(q0/q2); NO stage; MFMA (mh0, nh0)
#pragma unroll
        for (int nf = 0; nf < 4; ++nf)
#pragma unroll
            for (int ks = 0; ks < 2; ++ks) {
                const int col = wn * 64 + nf * 16 + m;
                const int chunk = (ks * 4 + quad) ^ (col & 7);
                bfr[nf * 2 + ks] = *(const short8*)&Bc[col * 64 + chunk * 8];
            }
#pragma unroll
        for (int t = 0; t < 4; ++t)
#pragma unroll
            for (int ks = 0; ks < 2; ++ks) {
                const int row = wm * 128 + t * 16 + m;
                const int chunk = (ks * 4 + quad) ^ (row & 7);
                afr[t * 2 + ks] = *(const short8*)&Ac[row * 64 + chunk * 8];
            }
        __builtin_amdgcn_s_barrier();
        __builtin_amdgcn_s_setprio(1);
#pragma unroll
        for (int t = 0; t < 4; ++t)
#pragma unroll
            for (int u = 0; u < 2; ++u)
#pragma unroll
                for (int ks = 0; ks < 2; ++ks)
                    acc[t][u] = __builtin_amdgcn_mfma_f32_16x16x32_bf16(
                        afr[t * 2 + ks], bfr[u * 2 + ks], acc[t][u], 0, 0, 0);
        __builtin_amdgcn_s_setprio(0);
        __builtin_amdgcn_s_barrier();

        // ---- phase 1: stage A q0,q2 of kt+2; MFMA (mh0, nh1)
        if (pf) { STG_AQ(cur, 0, kt + 2); STG_AQ(cur, 2, kt + 2); }
        __builtin_amdgcn_s_barrier();
        __builtin_amdgcn_s_setprio(1);
#pragma unroll
        for (int t = 0; t < 4; ++t)
#pragma unroll
            for (int u = 2; u < 4; ++u)
#pragma unroll
                for (int ks = 0; ks < 2; ++ks)
                    acc[t][u] = __builtin_amdgcn_mfma_f32_16x16x32_bf16(
                        afr[t * 2 + ks], bfr[u * 2 + ks], acc[t][u], 0, 0, 0);
        __builtin_amdgcn_s_setprio(0);
        __builtin_amdgcn_s_barrier();

        // ---- phase 2: read A(q1/q3); stage Bh0 of kt+2; MFMA (mh1, nh0)
#pragma unroll
        for (int t = 0; t < 4; ++t)
#pragma unroll
            for (int ks = 0; ks < 2; ++ks) {
                const int row = wm * 128 + (4 + t) * 16 + m;
                const int chunk = (ks * 4 + quad) ^ (row & 7);
                afr[t * 2 + ks] = *(const short8*)&Ac[row * 64 + chunk * 8];
            }
        __builtin_amdgcn_sched_barrier(0);
        if (pf) STG_BH(cur, 0, kt + 2);
        __builtin_amdgcn_s_barrier();
        __builtin_amdgcn_s_setprio(1);
#pragma unroll
        for (int t = 0; t < 4; ++t)
#pragma unroll
            for (int u = 0; u < 2; ++u)
#pragma unroll
                for (int ks = 0; ks < 2; ++ks)
                    acc[4 + t][u] = __builtin_amdgcn_mfma_f32_16x16x32_bf16(
                        afr[t * 2 + ks], bfr[u * 2 + ks], acc[4 + t][u], 0, 0, 0);
        __builtin_amdgcn_s_setprio(0);
        __builtin_amdgcn_s_barrier();

        // ---- phase 3: stage Bh1 + A q1,q3 of kt+2; MFMA (mh1, nh1); vmcnt
        if (pf) {
            STG_BH(cur, 1, kt + 2);
            STG_AQ(cur, 1, kt + 2); STG_AQ(cur, 3, kt + 2);
        }
        __builtin_amdgcn_s_barrier();
        __builtin_amdgcn_s_setprio(1);
#pragma unroll
        for (int t = 0; t < 4; ++t)
#pragma unroll
            for (int u = 2; u < 4; ++u)
#pragma unroll
                for (int ks = 0; ks < 2; ++ks)
                    acc[4 + t][u] = __builtin_amdgcn_mfma_f32_16x16x32_bf16(
                        afr[t * 2 + ks], bfr[u * 2 + ks], acc[4 + t][u], 0, 0, 0);
        __builtin_amdgcn_s_setprio(0);
        if (kt <= NT - 3) {
            asm volatile("s_waitcnt vmcnt(8)" ::: "memory");  // tile kt+1 landed
        } else {
            asm volatile("s_waitcnt vmcnt(0)" ::: "memory");  // drain tail
        }
        __builtin_amdgcn_s_barrier();
    }
#undef STG_AH
#undef STG_BH
#undef STG_AQ

    const int row0 = bm * 256 + wm * 128;
    const int col0 = bn * 256 + wn * 64;
#pragma unroll
    for (int mf = 0; mf < 8; ++mf) {
#pragma unroll
        for (int nf = 0; nf < 4; ++nf) {
            const int col = col0 + nf * 16 + m;
            const float bv = bias[col];
#pragma unroll
            for (int r = 0; r < 4; ++r) {
                const int row = row0 + mf * 16 + quad * 4 + r;
                float v = fast_tanh(acc[mf][nf][r] + bv);
                Xout[(size_t)row * ldout + col] = f32_to_bf16(v);
            }
        }
    }
}

// ---------------------------------------------------------------------------
// Pooling: 2-stage (8 row-slices); stage 2 writes TRANSPOSED gbufT[f][graph].
// ---------------------------------------------------------------------------
__global__ __launch_bounds__(256) void pool_partial(const unsigned short* __restrict__ h,
                                                    const int* __restrict__ batch,
                                                    float* __restrict__ part) {
    const int gi = blockIdx.x, rs = blockIdx.y, t = threadIdx.x;
    int lo = 0, hi = NN;
    while (lo < hi) { int mid = (lo + hi) >> 1; if (batch[mid] < gi) lo = mid + 1; else hi = mid; }
    const int start = lo;
    hi = NN;
    while (lo < hi) { int mid = (lo + hi) >> 1; if (batch[mid] < gi + 1) lo = mid + 1; else hi = mid; }
    const int end = lo;
    const int len = end - start;
    const int q = (len + 7) >> 3;
    int r0 = start + rs * q;
    int r1 = r0 + q; if (r1 > end) r1 = end; if (r0 > end) r0 = end;
    float mx0 = -INFINITY, mx1 = -INFINITY, s0 = 0.f, s1 = 0.f;
    int i = r0;
    for (; i + 2 <= r1; i += 2) {
        unsigned int d0 = *(const unsigned int*)(h + (size_t)i * 1024 + t * 2);
        unsigned int d1 = *(const unsigned int*)(h + (size_t)(i + 1) * 1024 + t * 2);
        float v0 = bf16_to_f32((unsigned short)(d0 & 0xFFFFu));
        float v1 = bf16_to_f32((unsigned short)(d0 >> 16));
        float w0 = bf16_to_f32((unsigned short)(d1 & 0xFFFFu));
        float w1 = bf16_to_f32((unsigned short)(d1 >> 16));
        mx0 = fmaxf(mx0, fmaxf(v0, w0)); mx1 = fmaxf(mx1, fmaxf(v1, w1));
        s0 += v0 + w0; s1 += v1 + w1;
    }
    for (; i < r1; ++i) {
        unsigned int d0 = *(const unsigned int*)(h + (size_t)i * 1024 + t * 2);
        float v0 = bf16_to_f32((unsigned short)(d0 & 0xFFFFu));
        float v1 = bf16_to_f32((unsigned short)(d0 >> 16));
        mx0 = fmaxf(mx0, v0); mx1 = fmaxf(mx1, v1);
        s0 += v0; s1 += v1;
    }
    float* p = part + ((size_t)gi * 8 + rs) * 1024;
    p[t * 2] = mx0; p[t * 2 + 1] = mx1;
    p[512 + t * 2] = s0; p[512 + t * 2 + 1] = s1;
}

__global__ __launch_bounds__(256) void pool_combine(const float* __restrict__ part,
                                                    const int* __restrict__ batch,
                                                    float* __restrict__ gT) {
    const int gi = blockIdx.x, t = threadIdx.x;
    int lo = 0, hi = NN;
    while (lo < hi) { int mid = (lo + hi) >> 1; if (batch[mid] < gi) lo = mid + 1; else hi = mid; }
    const int start = lo;
    hi = NN;
    while (lo < hi) { int mid = (lo + hi) >> 1; if (batch[mid] < gi + 1) lo = mid + 1; else hi = mid; }
    int cnt = lo - start; if (cnt < 1) cnt = 1;
    const float inv = 1.0f / (float)cnt;
    float mx0 = -INFINITY, mx1 = -INFINITY, s0 = 0.f, s1 = 0.f;
#pragma unroll
    for (int rs = 0; rs < 8; ++rs) {
        const float* p = part + ((size_t)gi * 8 + rs) * 1024;
        mx0 = fmaxf(mx0, p[t * 2]); mx1 = fmaxf(mx1, p[t * 2 + 1]);
        s0 += p[512 + t * 2]; s1 += p[512 + t * 2 + 1];
    }
    gT[(size_t)(2 * t) * 64 + gi]        = mx0;
    gT[(size_t)(2 * t + 1) * 64 + gi]    = mx1;
    gT[(size_t)(512 + 2 * t) * 64 + gi]  = s0 * inv;
    gT[(size_t)(512 + 2 * t + 1) * 64 + gi] = s1 * inv;
}

// ---------------------------------------------------------------------------
// MLP: split-K fp32 GEMM (LDS-staged) + combine
// ---------------------------------------------------------------------------
__global__ __launch_bounds__(256) void mlp_splitk(const float* __restrict__ ginT, // [K][64]
                                                  const float* __restrict__ W,    // [K][Ndim]
                                                  int Ndim,
                                                  float* __restrict__ partial) {  // [KB][64][Ndim]
    __shared__ float gsT[64][68];
    __shared__ float Ws[64][68];
    const int t = threadIdx.x;
    const int wv = t >> 6, l = t & 63;
    const int nb = blockIdx.x, kb = blockIdx.y;
    const int n0 = nb * 64;
    const int gr = t >> 2;
    const int c4 = (t & 3) * 16;
    float acc[16] = {};
#pragma unroll
    for (int sub = 0; sub < 2; ++sub) {
        const int k0 = kb * 128 + sub * 64;
        __syncthreads();
        {
            const float4* gsrc = (const float4*)(ginT + (size_t)(k0 + gr) * 64 + c4);
            float4* gd = (float4*)&gsT[gr][c4];
            gd[0] = gsrc[0]; gd[1] = gsrc[1]; gd[2] = gsrc[2]; gd[3] = gsrc[3];
            const float4* wsrc = (const float4*)(W + (size_t)(k0 + gr) * Ndim + n0 + c4);
            float4* wd = (float4*)&Ws[gr][c4];
            wd[0] = wsrc[0]; wd[1] = wsrc[1]; wd[2] = wsrc[2]; wd[3] = wsrc[3];
        }
        __syncthreads();
#pragma unroll 4
        for (int kk = 0; kk < 64; ++kk) {
            const float wval = Ws[kk][l];
            const float4* gv = (const float4*)&gsT[kk][wv * 16];
            float4 g0 = gv[0], g1 = gv[1], g2 = gv[2], g3 = gv[3];
            acc[0]  = fmaf(g0.x, wval, acc[0]);  acc[1]  = fmaf(g0.y, wval, acc[1]);
            acc[2]  = fmaf(g0.z, wval, acc[2]);  acc[3]  = fmaf(g0.w, wval, acc[3]);
            acc[4]  = fmaf(g1.x, wval, acc[4]);  acc[5]  = fmaf(g1.y, wval, acc[5]);
            acc[6]  = fmaf(g1.z, wval, acc[6]);  acc[7]  = fmaf(g1.w, wval, acc[7]);
            acc[8]  = fmaf(g2.x, wval, acc[8]);  acc[9]  = fmaf(g2.y, wval, acc[9]);
            acc[10] = fmaf(g2.z, wval, acc[10]); acc[11] = fmaf(g2.w, wval, acc[11]);
            acc[12] = fmaf(g3.x, wval, acc[12]); acc[13] = fmaf(g3.y, wval, acc[13]);
            acc[14] = fmaf(g3.z, wval, acc[14]); acc[15] = fmaf(g3.w, wval, acc[15]);
        }
    }
    float* p = partial + ((size_t)kb * 64) * Ndim;
#pragma unroll
    for (int g = 0; g < 16; ++g)
        p[(size_t)(wv * 16 + g) * Ndim + n0 + l] = acc[g];
}

__global__ __launch_bounds__(256) void mlp_combine(const float* __restrict__ partial, int nparts,
                                                   const float* __restrict__ bias, int Ndim,
                                                   float* __restrict__ outN,
                                                   float* __restrict__ outT) {
    const int idx = blockIdx.x * 256 + threadIdx.x;
    if (idx >= 64 * Ndim) return;
    const int g = idx / Ndim, n = idx - g * Ndim;
    float s = bias[n];
    for (int kb = 0; kb < nparts; ++kb)
        s += partial[((size_t)kb * 64 + g) * Ndim + n];
    const float v = fast_tanh(s);
    if (outN) outN[(size_t)g * Ndim + n] = v;
    if (outT) outT[(size_t)n * 64 + g] = v;
}

// ---------------------------------------------------------------------------
// Head: lane t covers k = t*8..t*8+7; wave butterfly reduce per class.
// ---------------------------------------------------------------------------
__global__ __launch_bounds__(64) void head_kernel(const float* __restrict__ g2,
                                                  const float* __restrict__ W,
                                                  const float* __restrict__ b,
                                                  float* __restrict__ out) {
    const int gi = blockIdx.x, t = threadIdx.x;
    const float4* gp = (const float4*)(g2 + (size_t)gi * HH + t * 8);
    float4 ga = gp[0], gb = gp[1];
    float gv[8] = {ga.x, ga.y, ga.z, ga.w, gb.x, gb.y, gb.z, gb.w};
    float logits[CC];
#pragma unroll
    for (int c = 0; c < CC; ++c) {
        float p = 0.f;
#pragma unroll
        for (int j = 0; j < 8; ++j)
            p = fmaf(gv[j], W[(t * 8 + j) * CC + c], p);
#pragma unroll
        for (int off = 32; off > 0; off >>= 1)
            p += __shfl_xor(p, off, 64);
        logits[c] = p + b[c];
    }
    if (t == 0) {
        float mx = logits[0];
#pragma unroll
        for (int c = 1; c < CC; ++c) mx = fmaxf(mx, logits[c]);
        float s = 0.f;
#pragma unroll
        for (int c = 0; c < CC; ++c) s += expf(logits[c] - mx);
        float lse = mx + logf(s);
#pragma unroll
        for (int c = 0; c < CC; ++c) out[(size_t)gi * CC + c] = logits[c] - lse;
    }
}

// ---------------------------------------------------------------------------
extern "C" void kernel_launch(void* const* d_in, const int* in_sizes, int n_in,
                              void* d_out, int out_size, void* d_ws, size_t ws_size,
                              hipStream_t stream) {
    const float* x       = (const float*)d_in[0];
    const int*   ei      = (const int*)d_in[1];
    const int*   batch   = (const int*)d_in[2];
    const float* w_root0 = (const float*)d_in[3];
    const float* w_rel0  = (const float*)d_in[4];
    const float* b0      = (const float*)d_in[5];
    const float* w_root  = (const float*)d_in[6];
    const float* w_rel   = (const float*)d_in[7];
    const float* bvec    = (const float*)d_in[8];
    const float* lin1_w  = (const float*)d_in[9];
    const float* lin1_b  = (const float*)d_in[10];
    const float* lin2_w  = (const float*)d_in[11];
    const float* lin2_b  = (const float*)d_in[12];
    const float* lin3_w  = (const float*)d_in[13];
    const float* lin3_b  = (const float*)d_in[14];
    float* out = (float*)d_out;

    char* w = (char*)d_ws;
    size_t off = 0;
    auto alloc = [&](size_t bytes) -> char* {
        char* p = w + off;
        off += (bytes + 255) & ~(size_t)255;
        return p;
    };
    unsigned short* Xa  = (unsigned short*)alloc((size_t)NN * 1024 * 2);
    unsigned short* Xb  = (unsigned short*)alloc((size_t)NN * 1024 * 2);
    unsigned short* X0  = (unsigned short*)alloc((size_t)NN * 64 * 2);
    unsigned short* WT0 = (unsigned short*)alloc(512 * 64 * 2);
    unsigned short* WTs = (unsigned short*)alloc((size_t)4 * 512 * 1024 * 2);
    int* counts   = (int*)alloc((size_t)(NN + 256) * 4);  // counts + degHist contiguous
    int* degHist  = counts + NN;
    int* degCursor= (int*)alloc(256 * 4);
    int* perm     = (int*)alloc((size_t)NN * 4);
    int* pDeg     = (int*)alloc((size_t)NN * 4);
    int* iperm    = (int*)alloc((size_t)NN * 4);
    int* pRowStart= (int*)alloc((size_t)(NN + 1) * 4);
    int* pCursor  = (int*)alloc((size_t)NN * 4);
    int* pssrc    = (int*)alloc((size_t)EE * 4);
    float* gbufT  = (float*)alloc((size_t)1024 * 64 * 4);
    float* g1T    = (float*)alloc((size_t)512 * 64 * 4);
    float* g2buf  = (float*)alloc((size_t)GG * 512 * 4);
    float* mlpPart = (float*)alloc((size_t)8 * 64 * 512 * 4);
    float* part   = (float*)X0;   // pool partials alias X0 (dead after layer 0); 2 MB

    const int* esrc = ei;
    const int* edst = ei + EE;

    // prep; degree hist; parallel degree-sort; pDeg scan; direct edge scatter.
    prep_all_kernel<<<4649, 256, 0, stream>>>(w_root0, w_rel0, WT0, w_root, w_rel, WTs, x, X0, counts);
    hist_kernel<<<2048, 256, 0, stream>>>(edst, counts);
    deg_hist_kernel<<<128, 256, 0, stream>>>(counts, degHist);
    deg_scan_kernel<<<1, 256, 0, stream>>>(degHist, degCursor);
    deg_scatter_kernel<<<128, 256, 0, stream>>>(counts, degCursor, perm, pDeg, iperm);
    scan_kernel<<<1, 1024, 0, stream>>>(pDeg, pRowStart, pCursor);
    scatter_kernel<<<2048, 256, 0, stream>>>(esrc, edst, iperm, pCursor, pssrc);

    // layer 0: F=32 -> H  (permuted CSR). Grid (256,4): N=512 needs 4 bn-blocks
    // (R9 failure was dim3(256,1) here -- cols 128..511 stale).
    agg_kernel<<<512, 256, 0, stream>>>(X0, X0 + 32, pRowStart, pssrc, perm);
    gemm_bias_tanh<<<dim3(256, 4), 256, 0, stream>>>(X0, 64, 64, WT0, b0, Xa, 1024);

    // layers 1..4: WITHIN-PROBE A/B (rule #13): layers 1,3 = gemm256 8-phase;
    // layers 2,4 = proven 128^2 multi-block/CU. Same run, same clocks ->
    // the counter CSV decides which GEMM structure survives.
    agg_slice_kernel<<<4096, 256, 0, stream>>>(Xa, Xa + 512, pRowStart, pssrc, perm);
    gemm256_bias_tanh<<<256, 512, 0, stream>>>(Xa, 1024, 1024, WTs + 0 * 524288, bvec + 0, Xb, 1024);
    agg_slice_kernel<<<4096, 256, 0, stream>>>(Xb, Xb + 512, pRowStart, pssrc, perm);
    gemm_bias_tanh<<<dim3(256, 4), 256, 0, stream>>>(Xb, 1024, 1024, WTs + 1 * 524288, bvec + 512, Xa, 1024);
    agg_slice_kernel<<<4096, 256, 0, stream>>>(Xa, Xa + 512, pRowStart, pssrc, perm);
    gemm256_bias_tanh<<<256, 512, 0, stream>>>(Xa, 1024, 1024, WTs + 2 * 524288, bvec + 1024, Xb, 1024);
    agg_slice_kernel<<<4096, 256, 0, stream>>>(Xb, Xb + 512, pRowStart, pssrc, perm);
    gemm_bias_tanh<<<dim3(256, 4), 256, 0, stream>>>(Xb, 1024, 1024, WTs + 3 * 524288, bvec + 1536, Xa, 1024);

    // pooling + MLP tail (LDS-staged split-K GEMMs)
    pool_partial<<<dim3(GG, 8), 256, 0, stream>>>(Xa, batch, part);
    pool_combine<<<GG, 256, 0, stream>>>(part, batch, gbufT);
    mlp_splitk<<<dim3(8, 8), 256, 0, stream>>>(gbufT, lin1_w, 512, mlpPart);
    mlp_combine<<<128, 256, 0, stream>>>(mlpPart, 8, lin1_b, 512, nullptr, g1T);
    mlp_splitk<<<dim3(8, 4), 256, 0, stream>>>(g1T, lin2_w, 512, mlpPart);
    mlp_combine<<<128, 256, 0, stream>>>(mlpPart, 4, lin2_b, 512, g2buf, nullptr);
    head_kernel<<<GG, 64, 0, stream>>>(g2buf, lin3_w, lin3_b, out);
}

// Round 11
// 578.763 us; speedup vs baseline: 1.0171x; 1.0171x over previous
//
#include <hip/hip_runtime.h>
#include <hip/hip_bf16.h>
#include <math.h>

#define NN 32768
#define EE 524288
#define FF 32
#define HH 512
#define GG 64
#define CC 10

typedef __attribute__((ext_vector_type(8))) short short8;
typedef __attribute__((ext_vector_type(4))) float floatx4;
typedef __attribute__((ext_vector_type(4))) unsigned int uintx4;

__device__ __forceinline__ float bf16_to_f32(unsigned short u) {
    union { unsigned int u; float f; } v;
    v.u = ((unsigned int)u) << 16;
    return v.f;
}
__device__ __forceinline__ unsigned short f32_to_bf16(float f) {
    union { float f; unsigned int u; } v;
    v.f = f;
    unsigned int u = v.u;
    u += 0x7FFFu + ((u >> 16) & 1u);   // round-to-nearest-even
    return (unsigned short)(u >> 16);
}
// tanh(x) = 1 - 2/(1+e^{2x});  exact at +-inf, err far below bf16 grid
__device__ __forceinline__ float fast_tanh(float x) {
    float e = __expf(2.0f * x);
    return 1.0f - 2.0f * __builtin_amdgcn_rcpf(e + 1.0f);
}

// ---------------------------------------------------------------------------
// Merged prep: LDS-tiled weight transpose + X0 cast + counts/degHist/degBump
// zero. blocks [0,8): WT0; [8,520): WTs; [520,4616): X0 cast; [4616,4649):
// zero (counts NN + degHist 256 + degBump 256 ints, contiguous).
// ---------------------------------------------------------------------------
__global__ __launch_bounds__(256) void prep_all_kernel(const float* __restrict__ wr0, const float* __restrict__ wl0,
                                unsigned short* __restrict__ WT0,
                                const float* __restrict__ wroot, const float* __restrict__ wrel,
                                unsigned short* __restrict__ WTs,
                                const float* __restrict__ x, unsigned short* __restrict__ X0,
                                int* __restrict__ counts) {
    const int b = blockIdx.x;
    const int tid = threadIdx.x;
    if (b < 520) {
        __shared__ unsigned short tile[64][65];
        const int ty = tid >> 6, tx = tid & 63;
        if (b < 8) {
            const int n0 = b * 64;
#pragma unroll
            for (int q = 0; q < 16; ++q) {
                const int k = ty * 16 + q;
                const float v = (k < 32) ? wr0[k * 512 + n0 + tx]
                                         : wl0[(k - 32) * 512 + n0 + tx];
                tile[k][tx] = f32_to_bf16(v);
            }
            __syncthreads();
#pragma unroll
            for (int q = 0; q < 16; ++q) {
                const int n = n0 + ty * 16 + q;
                WT0[n * 64 + tx] = tile[tx][ty * 16 + q];
            }
        } else {
            const int bb = b - 8;          // 0..511
            const int l = bb >> 7;         // layer
            const int r = bb & 127;        // 16 ktile x 8 ntile
            const int k0 = (r >> 3) * 64;  // multiple of 64 -> never straddles 512
            const int n0 = (r & 7) * 64;
            const float* Wl = (k0 < 512) ? wroot + (size_t)l * 262144
                                         : wrel + (size_t)l * 262144;
            const int kb = (k0 < 512) ? k0 : k0 - 512;
#pragma unroll
            for (int q = 0; q < 16; ++q) {
                const int kk = ty * 16 + q;
                tile[kk][tx] = f32_to_bf16(Wl[(size_t)(kb + kk) * 512 + n0 + tx]);
            }
            __syncthreads();
#pragma unroll
            for (int q = 0; q < 16; ++q) {
                const int n = n0 + ty * 16 + q;
                WTs[(size_t)l * 524288 + (size_t)n * 1024 + k0 + tx] = tile[tx][ty * 16 + q];
            }
        }
    } else if (b < 4616) {
        const int t = (b - 520) * 256 + tid; // NN*32
        const int i = t >> 5, c = t & 31;
        X0[(size_t)i * 64 + c] = f32_to_bf16(x[t]);
    } else {
        const int t4 = (b - 4616) * 256 + tid;   // counts+degHist+degBump = (NN+512)/4 = 8320 int4
        if (t4 < 8320) {
            int4 z; z.x = 0; z.y = 0; z.z = 0; z.w = 0;
            ((int4*)counts)[t4] = z;
        }
    }
}

// ---------------------------------------------------------------------------
// hist: per-dst degree counts (counts zeroed by prep).
// ---------------------------------------------------------------------------
__global__ void hist_kernel(const int* __restrict__ dst, int* __restrict__ counts) {
    int e = blockIdx.x * blockDim.x + threadIdx.x;
    if (e < EE) atomicAdd(&counts[dst[e]], 1);
}

// degree histogram (bin = 255-deg -> descending sort), LDS pre-aggregated,
// 128 blocks.
__global__ __launch_bounds__(256) void deg_hist_kernel(const int* __restrict__ counts,
                                                       int* __restrict__ degHist) {
    __shared__ int lh[256];
    lh[threadIdx.x] = 0;
    __syncthreads();
    int i = blockIdx.x * 256 + threadIdx.x;
    int d = counts[i]; if (d > 255) d = 255;
    atomicAdd(&lh[255 - d], 1);
    __syncthreads();
    int v = lh[threadIdx.x];
    if (v) atomicAdd(&degHist[threadIdx.x], v);
}

// deg_scatter v2 (R11): folds the old deg_scan in -- each block recomputes
// the 256-bin exclusive scan of degHist in LDS (trivial) and uses a separate
// zeroed degBump[] for cross-block bin cursoring. Same perm semantics,
// one fewer kernel launch.
__global__ __launch_bounds__(256) void deg_scatter_kernel(const int* __restrict__ counts,
                                                          const int* __restrict__ degHist,
                                                          int* __restrict__ degBump,
                                                          int* __restrict__ perm,
                                                          int* __restrict__ pDeg,
                                                          int* __restrict__ iperm) {
    __shared__ int lh[256];
    __shared__ int sh[256];
    __shared__ int base[256];
    const int t = threadIdx.x;
    lh[t] = 0;
    const int own = degHist[t];
    sh[t] = own;
    __syncthreads();
    for (int off = 1; off < 256; off <<= 1) {
        int v = (t >= off) ? sh[t - off] : 0;
        __syncthreads();
        sh[t] += v;
        __syncthreads();
    }
    const int excl = sh[t] - own;   // exclusive prefix of bin t
    int i = blockIdx.x * 256 + t;
    int dtrue = counts[i];
    int d = dtrue > 255 ? 255 : dtrue;
    int bin = 255 - d;
    int lr = atomicAdd(&lh[bin], 1);      // local rank within (block, bin)
    __syncthreads();
    int c = lh[t];
    if (c) base[t] = excl + atomicAdd(&degBump[t], c);
    __syncthreads();
    int p = base[bin] + lr;
    perm[p] = i;
    pDeg[p] = dtrue;
    iperm[i] = p;
}
// scan pDeg (permuted order) -> pRowStart, pCursor (1024thr x 32/thread)
__global__ __launch_bounds__(1024) void scan_kernel(const int* __restrict__ pDeg,
                                                    int* __restrict__ pRowStart,
                                                    int* __restrict__ pCursor) {
    __shared__ int part[1024];
    const int t = threadIdx.x;
    const int base = t * 32;
    int local[32];
    const int4* cp = (const int4*)(pDeg + base);
    int s = 0;
#pragma unroll
    for (int ii = 0; ii < 8; ++ii) {
        int4 v = cp[ii];
        local[ii * 4 + 0] = v.x; local[ii * 4 + 1] = v.y;
        local[ii * 4 + 2] = v.z; local[ii * 4 + 3] = v.w;
        s += v.x + v.y + v.z + v.w;
    }
    part[t] = s;
    __syncthreads();
    for (int off = 1; off < 1024; off <<= 1) {
        int v = (t >= off) ? part[t - off] : 0;
        __syncthreads();
        part[t] += v;
        __syncthreads();
    }
    int run = part[t] - s;
#pragma unroll
    for (int i = 0; i < 32; ++i) {
        pRowStart[base + i] = run;
        pCursor[base + i] = run;
        run += local[i];
    }
    if (t == 1023) pRowStart[NN] = run;
}

// ---------------------------------------------------------------------------
// scatter: edges go DIRECTLY into permuted CSR (no ssrc / edge_copy).
// ---------------------------------------------------------------------------
__global__ void scatter_kernel(const int* __restrict__ src, const int* __restrict__ dst,
                               const int* __restrict__ iperm,
                               int* __restrict__ pCursor, int* __restrict__ pssrc) {
    int e = blockIdx.x * blockDim.x + threadIdx.x;
    if (e < EE) {
        int p = iperm[dst[e]];
        int q = atomicAdd(&pCursor[p], 1);
        pssrc[q] = src[e];
    }
}

// ---------------------------------------------------------------------------
__device__ __forceinline__ void acc8(float* a, uint4 d) {
    a[0] += bf16_to_f32((unsigned short)(d.x & 0xFFFFu));
    a[1] += bf16_to_f32((unsigned short)(d.x >> 16));
    a[2] += bf16_to_f32((unsigned short)(d.y & 0xFFFFu));
    a[3] += bf16_to_f32((unsigned short)(d.y >> 16));
    a[4] += bf16_to_f32((unsigned short)(d.z & 0xFFFFu));
    a[5] += bf16_to_f32((unsigned short)(d.z >> 16));
    a[6] += bf16_to_f32((unsigned short)(d.w & 0xFFFFu));
    a[7] += bf16_to_f32((unsigned short)(d.w >> 16));
}
__device__ __forceinline__ void acc8v(float* a, uintx4 d) {
    a[0] += bf16_to_f32((unsigned short)(d[0] & 0xFFFFu));
    a[1] += bf16_to_f32((unsigned short)(d[0] >> 16));
    a[2] += bf16_to_f32((unsigned short)(d[1] & 0xFFFFu));
    a[3] += bf16_to_f32((unsigned short)(d[1] >> 16));
    a[4] += bf16_to_f32((unsigned short)(d[2] & 0xFFFFu));
    a[5] += bf16_to_f32((unsigned short)(d[2] >> 16));
    a[6] += bf16_to_f32((unsigned short)(d[3] & 0xFFFFu));
    a[7] += bf16_to_f32((unsigned short)(d[3] >> 16));
}

// Layer-0 agg (cols=32), permuted CSR: 16 nodes/wave x 4 lanes/node.
__global__ __launch_bounds__(256) void agg_kernel(const unsigned short* __restrict__ Xh,
                                                  unsigned short* __restrict__ Xagg,
                                                  const int* __restrict__ pRowStart,
                                                  const int* __restrict__ pssrc,
                                                  const int* __restrict__ perm) {
    const int p = blockIdx.x * 64 + (threadIdx.x >> 2);
    const int lc = threadIdx.x & 3;
    const int node = perm[p];
    const int s = pRowStart[p];
    const int e = pRowStart[p + 1];
    float a[8] = {0.f, 0.f, 0.f, 0.f, 0.f, 0.f, 0.f, 0.f};
    const unsigned short* base = Xh + lc * 8;
    int i = s;
    for (; i + 4 <= e; i += 4) {
        int j0 = pssrc[i], j1 = pssrc[i + 1], j2 = pssrc[i + 2], j3 = pssrc[i + 3];
        uint4 d0 = *(const uint4*)(base + (size_t)j0 * 64);
        uint4 d1 = *(const uint4*)(base + (size_t)j1 * 64);
        uint4 d2 = *(const uint4*)(base + (size_t)j2 * 64);
        uint4 d3 = *(const uint4*)(base + (size_t)j3 * 64);
        acc8(a, d0); acc8(a, d1); acc8(a, d2); acc8(a, d3);
    }
    for (; i < e; ++i) {
        int j = pssrc[i];
        uint4 d = *(const uint4*)(base + (size_t)j * 64);
        acc8(a, d);
    }
    unsigned short* out = Xagg + (size_t)node * 64 + lc * 8;
#pragma unroll
    for (int c = 0; c < 8; ++c) out[c] = f32_to_bf16(a[c]);
}

// ---------------------------------------------------------------------------
// Column-sliced XCD-affine agg v6 (proven config: ~47us, L2-request-rate
// bound; depth-16 asm pipeline; plain L2-cached accesses).
// ---------------------------------------------------------------------------
#define GLOAD(dreg, voff) \
    asm volatile("buffer_load_dwordx4 %0, %1, %2, 0 offen" \
                 : "=v"(dreg) : "v"(voff), "s"(srsrc))

__global__ __launch_bounds__(256, 3) void agg_slice_kernel(const unsigned short* __restrict__ Xh,
                                                           unsigned short* __restrict__ Xagg,
                                                           const int* __restrict__ pRowStart,
                                                           const int* __restrict__ pssrc,
                                                           const int* __restrict__ perm) {
    const int slice = blockIdx.x & 7;
    const int pair = blockIdx.x >> 3;          // 0..511
    const int wv = threadIdx.x >> 6;
    const int lane = threadIdx.x & 63;
    const int ln = lane >> 3;
    const int lc = lane & 7;
    const int colOff = slice * 64 + lc * 8;
    const unsigned short* base = Xh + colOff;     // tail path (compiler loads)
    uintx4 srsrc;
    {
        union { const unsigned short* p; unsigned int u[2]; } ba;
        ba.p = Xh + slice * 64;
        srsrc[0] = ba.u[0];
        srsrc[1] = ba.u[1] & 0xFFFFu;   // stride = 0
        srsrc[2] = 0xFFFFFFFFu;         // num_records: bounds check disabled
        srsrc[3] = 0x00020000u;         // raw untyped dword
    }
    const unsigned int lcoff = (unsigned int)(lc << 4);
#pragma unroll
    for (int half = 0; half < 2; ++half) {
        const int nb = half ? (1023 - pair) : pair;
        const int p = nb * 32 + wv * 8 + ln;
        const int node = perm[p];
        const int s = pRowStart[p];
        const int e = pRowStart[p + 1];
        float a[8] = {0.f, 0.f, 0.f, 0.f, 0.f, 0.f, 0.f, 0.f};
        int i = s;
        for (; i + 16 <= e; i += 16) {
            unsigned int vo[16];
#pragma unroll
            for (int u = 0; u < 16; ++u)
                vo[u] = (((unsigned int)pssrc[i + u]) << 11) | lcoff;
            uintx4 d0, d1, d2, d3, d4, d5, d6, d7, d8, d9, d10, d11, d12, d13, d14, d15;
            __builtin_amdgcn_sched_barrier(0);
            GLOAD(d0, vo[0]);   GLOAD(d1, vo[1]);   GLOAD(d2, vo[2]);   GLOAD(d3, vo[3]);
            GLOAD(d4, vo[4]);   GLOAD(d5, vo[5]);   GLOAD(d6, vo[6]);   GLOAD(d7, vo[7]);
            GLOAD(d8, vo[8]);   GLOAD(d9, vo[9]);   GLOAD(d10, vo[10]); GLOAD(d11, vo[11]);
            GLOAD(d12, vo[12]); GLOAD(d13, vo[13]); GLOAD(d14, vo[14]); GLOAD(d15, vo[15]);
            asm volatile("s_waitcnt vmcnt(8)" ::: "memory");
            __builtin_amdgcn_sched_barrier(0);
            acc8v(a, d0); acc8v(a, d1); acc8v(a, d2); acc8v(a, d3);
            acc8v(a, d4); acc8v(a, d5); acc8v(a, d6); acc8v(a, d7);
            asm volatile("s_waitcnt vmcnt(0)" ::: "memory");
            __builtin_amdgcn_sched_barrier(0);
            acc8v(a, d8);  acc8v(a, d9);  acc8v(a, d10); acc8v(a, d11);
            acc8v(a, d12); acc8v(a, d13); acc8v(a, d14); acc8v(a, d15);
        }
        if (e - i >= 8) {
            unsigned int vo[8];
#pragma unroll
            for (int u = 0; u < 8; ++u)
                vo[u] = (((unsigned int)pssrc[i + u]) << 11) | lcoff;
            uintx4 d0, d1, d2, d3, d4, d5, d6, d7;
            __builtin_amdgcn_sched_barrier(0);
            GLOAD(d0, vo[0]); GLOAD(d1, vo[1]); GLOAD(d2, vo[2]); GLOAD(d3, vo[3]);
            GLOAD(d4, vo[4]); GLOAD(d5, vo[5]); GLOAD(d6, vo[6]); GLOAD(d7, vo[7]);
            asm volatile("s_waitcnt vmcnt(4)" ::: "memory");
            __builtin_amdgcn_sched_barrier(0);
            acc8v(a, d0); acc8v(a, d1); acc8v(a, d2); acc8v(a, d3);
            asm volatile("s_waitcnt vmcnt(0)" ::: "memory");
            __builtin_amdgcn_sched_barrier(0);
            acc8v(a, d4); acc8v(a, d5); acc8v(a, d6); acc8v(a, d7);
            i += 8;
        }
        for (; i + 4 <= e; i += 4) {
            int j0 = pssrc[i], j1 = pssrc[i + 1], j2 = pssrc[i + 2], j3 = pssrc[i + 3];
            uint4 e0 = *(const uint4*)(base + (size_t)j0 * 1024);
            uint4 e1 = *(const uint4*)(base + (size_t)j1 * 1024);
            uint4 e2 = *(const uint4*)(base + (size_t)j2 * 1024);
            uint4 e3 = *(const uint4*)(base + (size_t)j3 * 1024);
            acc8(a, e0); acc8(a, e1); acc8(a, e2); acc8(a, e3);
        }
        for (; i < e; ++i) {
            int j = pssrc[i];
            uint4 d = *(const uint4*)(base + (size_t)j * 1024);
            acc8(a, d);
        }
        unsigned short* out = Xagg + (size_t)node * 1024 + colOff;
#pragma unroll
        for (int c = 0; c < 8; ++c) out[c] = f32_to_bf16(a[c]);
    }
}

// ---------------------------------------------------------------------------
// bf16 MFMA GEMM 128x128: BK=64, XOR-swizzled LDS. Used for layer 0 (K=64).
// ---------------------------------------------------------------------------
__global__ __launch_bounds__(256, 4) void gemm_bias_tanh(const unsigned short* __restrict__ Xin,
                                                         int ldin, int K,
                                                         const unsigned short* __restrict__ WT,
                                                         const float* __restrict__ bias,
                                                         unsigned short* __restrict__ Xout,
                                                         int ldout) {
    __shared__ __align__(16) unsigned short As[128 * 64];
    __shared__ __align__(16) unsigned short Bs[128 * 64];
    const int tid = threadIdx.x;
    const int lane = tid & 63;
    const int wave = tid >> 6;
    const int wm = wave >> 1, wn = wave & 1;
    const int bm = blockIdx.x, bn = blockIdx.y;

    floatx4 acc[4][4] = {};

    const int lrow = lane >> 3;
    const int schunk = (lane & 7) ^ (lrow & 7);
    const unsigned short* Abase = Xin + (size_t)(bm * 128) * ldin;
    const unsigned short* Bbase = WT + (size_t)(bn * 128) * K;
    const int m = lane & 15;
    const int quad = lane >> 4;

    for (int k0 = 0; k0 < K; k0 += 64) {
        __syncthreads();
#pragma unroll
        for (int q = 0; q < 4; ++q) {
            const int rr = q * 32 + wave * 8;
            const int row = rr + lrow;
            const unsigned short* sa = Abase + (size_t)row * ldin + (k0 + schunk * 8);
            const unsigned short* sb = Bbase + (size_t)row * K + (k0 + schunk * 8);
            __builtin_amdgcn_global_load_lds(
                (const __attribute__((address_space(1))) void*)sa,
                (__attribute__((address_space(3))) void*)(&As[rr * 64]), 16, 0, 0);
            __builtin_amdgcn_global_load_lds(
                (const __attribute__((address_space(1))) void*)sb,
                (__attribute__((address_space(3))) void*)(&Bs[rr * 64]), 16, 0, 0);
        }
        __syncthreads();
#pragma unroll
        for (int half = 0; half < 2; ++half) {
            short8 af[4], bfr[4];
#pragma unroll
            for (int t = 0; t < 4; ++t) {
                const int row = wm * 64 + t * 16 + m;
                const int chunk = (half * 4 + quad) ^ (row & 7);
                af[t] = *(const short8*)&As[row * 64 + chunk * 8];
            }
#pragma unroll
            for (int t = 0; t < 4; ++t) {
                const int row = wn * 64 + t * 16 + m;
                const int chunk = (half * 4 + quad) ^ (row & 7);
                bfr[t] = *(const short8*)&Bs[row * 64 + chunk * 8];
            }
#pragma unroll
            for (int mt = 0; mt < 4; ++mt)
#pragma unroll
                for (int nt = 0; nt < 4; ++nt)
                    acc[mt][nt] = __builtin_amdgcn_mfma_f32_16x16x32_bf16(af[mt], bfr[nt],
                                                                          acc[mt][nt], 0, 0, 0);
        }
    }

    const int row0 = bm * 128 + wm * 64;
    const int col0 = bn * 128 + wn * 64;
#pragma unroll
    for (int mt = 0; mt < 4; ++mt) {
#pragma unroll
        for (int nt = 0; nt < 4; ++nt) {
            const int col = col0 + nt * 16 + m;
            const float bv = bias[col];
#pragma unroll
            for (int r = 0; r < 4; ++r) {
                const int row = row0 + mt * 16 + quad * 4 + r;
                float v = fast_tanh(acc[mt][nt][r] + bv);
                Xout[(size_t)row * ldout + col] = f32_to_bf16(v);
            }
        }
    }
}

// ---------------------------------------------------------------------------
// 256x256 8-phase bf16 MFMA GEMM, v2 (race-fixed, verified R4-R10).
// All four H-layers (best timed total: R8 all-gemm256 = 572.8us).
// ---------------------------------------------------------------------------
__device__ __forceinline__ void stage_half(const unsigned short* __restrict__ gsrc0,
                                           int ldg, unsigned short* ldsHalf,
                                           int w, int lane) {
#pragma unroll
    for (int q = 0; q < 2; ++q) {
        const int rb = q * 64 + w * 8;                       // wave-uniform row block (8 rows)
        const unsigned short* src = gsrc0 + (size_t)(rb + (lane >> 3)) * ldg
                                    + ((lane & 7) ^ (lane >> 3)) * 8;   // pre-swizzled source
        __builtin_amdgcn_global_load_lds(
            (const __attribute__((address_space(1))) void*)src,
            (__attribute__((address_space(3))) void*)(ldsHalf + rb * 64), 16, 0, 0);
    }
}
// stage one 64-row quarter: 1 load/wave (8 waves x 8 rows)
__device__ __forceinline__ void stage_q(const unsigned short* __restrict__ gsrc0,
                                        int ldg, unsigned short* ldsQ,
                                        int w, int lane) {
    const unsigned short* src = gsrc0 + (size_t)(w * 8 + (lane >> 3)) * ldg
                                + ((lane & 7) ^ (lane >> 3)) * 8;
    __builtin_amdgcn_global_load_lds(
        (const __attribute__((address_space(1))) void*)src,
        (__attribute__((address_space(3))) void*)(ldsQ + (w * 8) * 64), 16, 0, 0);
}

__global__ __launch_bounds__(512, 2) void gemm256_bias_tanh(
    const unsigned short* __restrict__ Xin, int ldin, int K,
    const unsigned short* __restrict__ WT, const float* __restrict__ bias,
    unsigned short* __restrict__ Xout, int ldout) {
    __shared__ __align__(16) unsigned short As[2][256 * 64];   // 64KB
    __shared__ __align__(16) unsigned short Bs[2][256 * 64];   // 64KB
    const int tid = threadIdx.x;
    const int lane = tid & 63;
    const int w = tid >> 6;                 // 0..7
    const int wm = w >> 2, wn = w & 3;      // 2 x 4 wave grid
    const int m = lane & 15, quad = lane >> 4;
    const int id = (int)blockIdx.x;
    const int bm = (id & 7) * 16 + (id >> 4);
    const int bn = (id >> 3) & 1;
    const int NT = K >> 6;

    const unsigned short* Abase = Xin + (size_t)(bm * 256) * ldin;
    const unsigned short* Bbase = WT + (size_t)(bn * 256) * K;

    floatx4 acc[8][4] = {};

#define STG_AH(buf, h, kt_) stage_half(Abase + (size_t)((h) * 128) * ldin + (kt_) * 64, ldin, \
                                       &As[buf][(h) * 128 * 64], w, lane)
#define STG_BH(buf, h, kt_) stage_half(Bbase + (size_t)((h) * 128) * K + (kt_) * 64, K, \
                                       &Bs[buf][(h) * 128 * 64], w, lane)
#define STG_AQ(buf, qr, kt_) stage_q(Abase + (size_t)((qr) * 64) * ldin + (kt_) * 64, ldin, \
                                     &As[buf][(qr) * 64 * 64], w, lane)

    // prologue: tiles 0 and 1 (16 loads/wave; first 8 are exactly tile 0)
    STG_BH(0, 0, 0); STG_BH(0, 1, 0); STG_AH(0, 0, 0); STG_AH(0, 1, 0);
    STG_BH(1, 0, 1); STG_BH(1, 1, 1); STG_AH(1, 0, 1); STG_AH(1, 1, 1);
    asm volatile("s_waitcnt vmcnt(8)" ::: "memory");   // tile 0 fully landed
    __builtin_amdgcn_s_barrier();

    for (int kt = 0; kt < NT; ++kt) {
        const int cur = kt & 1;
        const unsigned short* Ac = &As[cur][0];
        const unsigned short* Bc = &Bs[cur][0];
        const bool pf = (kt + 2 < NT);
        short8 afr[8], bfr[8];

        // ---- phase 0: read B(all) + A(q0/q2); NO stage; MFMA (mh0, nh0)
#pragma unroll
        for (int nf = 0; nf < 4; ++nf)
#pragma unroll
            for (int ks = 0; ks < 2; ++ks) {
                const int col = wn * 64 + nf * 16 + m;
                const int chunk = (ks * 4 + quad) ^ (col & 7);
                bfr[nf * 2 + ks] = *(const short8*)&Bc[col * 64 + chunk * 8];
            }
#pragma unroll
        for (int t = 0; t < 4; ++t)
#pragma unroll
            for (int ks = 0; ks < 2; ++ks) {
                const int row = wm * 128 + t * 16 + m;
                const int chunk = (ks * 4 + quad) ^ (row & 7);
                afr[t * 2 + ks] = *(const short8*)&Ac[row * 64 + chunk * 8];
            }
        __builtin_amdgcn_s_barrier();
        __builtin_amdgcn_s_setprio(1);
#pragma unroll
        for (int t = 0; t < 4; ++t)
#pragma unroll
            for (int u = 0; u < 2; ++u)
#pragma unroll
                for (int ks = 0; ks < 2; ++ks)
                    acc[t][u] = __builtin_amdgcn_mfma_f32_16x16x32_bf16(
                        afr[t * 2 + ks], bfr[u * 2 + ks], acc[t][u], 0, 0, 0);
        __builtin_amdgcn_s_setprio(0);
        __builtin_amdgcn_s_barrier();

        // ---- phase 1: stage A q0,q2 of kt+2; MFMA (mh0, nh1)
        if (pf) { STG_AQ(cur, 0, kt + 2); STG_AQ(cur, 2, kt + 2); }
        __builtin_amdgcn_s_barrier();
        __builtin_amdgcn_s_setprio(1);
#pragma unroll
        for (int t = 0; t < 4; ++t)
#pragma unroll
            for (int u = 2; u < 4; ++u)
#pragma unroll
                for (int ks = 0; ks < 2; ++ks)
                    acc[t][u] = __builtin_amdgcn_mfma_f32_16x16x32_bf16(
                        afr[t * 2 + ks], bfr[u * 2 + ks], acc[t][u], 0, 0, 0);
        __builtin_amdgcn_s_setprio(0);
        __builtin_amdgcn_s_barrier();

        // ---- phase 2: read A(q1/q3); stage Bh0 of kt+2; MFMA (mh1, nh0)
#pragma unroll
        for (int t = 0; t < 4; ++t)
#pragma unroll
            for (int ks = 0; ks < 2; ++ks) {
                const int row = wm * 128 + (4 + t) * 16 + m;
                const int chunk = (ks * 4 + quad) ^ (row & 7);
                afr[t * 2 + ks] = *(const short8*)&Ac[row * 64 + chunk * 8];
            }
        __builtin_amdgcn_sched_barrier(0);
        if (pf) STG_BH(cur, 0, kt + 2);
        __builtin_amdgcn_s_barrier();
        __builtin_amdgcn_s_setprio(1);
#pragma unroll
        for (int t = 0; t < 4; ++t)
#pragma unroll
            for (int u = 0; u < 2; ++u)
#pragma unroll
                for (int ks = 0; ks < 2; ++ks)
                    acc[4 + t][u] = __builtin_amdgcn_mfma_f32_16x16x32_bf16(
                        afr[t * 2 + ks], bfr[u * 2 + ks], acc[4 + t][u], 0, 0, 0);
        __builtin_amdgcn_s_setprio(0);
        __builtin_amdgcn_s_barrier();

        // ---- phase 3: stage Bh1 + A q1,q3 of kt+2; MFMA (mh1, nh1); vmcnt
        if (pf) {
            STG_BH(cur, 1, kt + 2);
            STG_AQ(cur, 1, kt + 2); STG_AQ(cur, 3, kt + 2);
        }
        __builtin_amdgcn_s_barrier();
        __builtin_amdgcn_s_setprio(1);
#pragma unroll
        for (int t = 0; t < 4; ++t)
#pragma unroll
            for (int u = 2; u < 4; ++u)
#pragma unroll
                for (int ks = 0; ks < 2; ++ks)
                    acc[4 + t][u] = __builtin_amdgcn_mfma_f32_16x16x32_bf16(
                        afr[t * 2 + ks], bfr[u * 2 + ks], acc[4 + t][u], 0, 0, 0);
        __builtin_amdgcn_s_setprio(0);
        if (kt <= NT - 3) {
            asm volatile("s_waitcnt vmcnt(8)" ::: "memory");  // tile kt+1 landed
        } else {
            asm volatile("s_waitcnt vmcnt(0)" ::: "memory");  // drain tail
        }
        __builtin_amdgcn_s_barrier();
    }
#undef STG_AH
#undef STG_BH
#undef STG_AQ

    const int row0 = bm * 256 + wm * 128;
    const int col0 = bn * 256 + wn * 64;
#pragma unroll
    for (int mf = 0; mf < 8; ++mf) {
#pragma unroll
        for (int nf = 0; nf < 4; ++nf) {
            const int col = col0 + nf * 16 + m;
            const float bv = bias[col];
#pragma unroll
            for (int r = 0; r < 4; ++r) {
                const int row = row0 + mf * 16 + quad * 4 + r;
                float v = fast_tanh(acc[mf][nf][r] + bv);
                Xout[(size_t)row * ldout + col] = f32_to_bf16(v);
            }
        }
    }
}

// ---------------------------------------------------------------------------
// Pooling: 2-stage (8 row-slices); stage 2 writes TRANSPOSED gbufT[f][graph].
// ---------------------------------------------------------------------------
__global__ __launch_bounds__(256) void pool_partial(const unsigned short* __restrict__ h,
                                                    const int* __restrict__ batch,
                                                    float* __restrict__ part) {
    const int gi = blockIdx.x, rs = blockIdx.y, t = threadIdx.x;
    int lo = 0, hi = NN;
    while (lo < hi) { int mid = (lo + hi) >> 1; if (batch[mid] < gi) lo = mid + 1; else hi = mid; }
    const int start = lo;
    hi = NN;
    while (lo < hi) { int mid = (lo + hi) >> 1; if (batch[mid] < gi + 1) lo = mid + 1; else hi = mid; }
    const int end = lo;
    const int len = end - start;
    const int q = (len + 7) >> 3;
    int r0 = start + rs * q;
    int r1 = r0 + q; if (r1 > end) r1 = end; if (r0 > end) r0 = end;
    float mx0 = -INFINITY, mx1 = -INFINITY, s0 = 0.f, s1 = 0.f;
    int i = r0;
    for (; i + 2 <= r1; i += 2) {
        unsigned int d0 = *(const unsigned int*)(h + (size_t)i * 1024 + t * 2);
        unsigned int d1 = *(const unsigned int*)(h + (size_t)(i + 1) * 1024 + t * 2);
        float v0 = bf16_to_f32((unsigned short)(d0 & 0xFFFFu));
        float v1 = bf16_to_f32((unsigned short)(d0 >> 16));
        float w0 = bf16_to_f32((unsigned short)(d1 & 0xFFFFu));
        float w1 = bf16_to_f32((unsigned short)(d1 >> 16));
        mx0 = fmaxf(mx0, fmaxf(v0, w0)); mx1 = fmaxf(mx1, fmaxf(v1, w1));
        s0 += v0 + w0; s1 += v1 + w1;
    }
    for (; i < r1; ++i) {
        unsigned int d0 = *(const unsigned int*)(h + (size_t)i * 1024 + t * 2);
        float v0 = bf16_to_f32((unsigned short)(d0 & 0xFFFFu));
        float v1 = bf16_to_f32((unsigned short)(d0 >> 16));
        mx0 = fmaxf(mx0, v0); mx1 = fmaxf(mx1, v1);
        s0 += v0; s1 += v1;
    }
    float* p = part + ((size_t)gi * 8 + rs) * 1024;
    p[t * 2] = mx0; p[t * 2 + 1] = mx1;
    p[512 + t * 2] = s0; p[512 + t * 2 + 1] = s1;
}

__global__ __launch_bounds__(256) void pool_combine(const float* __restrict__ part,
                                                    const int* __restrict__ batch,
                                                    float* __restrict__ gT) {
    const int gi = blockIdx.x, t = threadIdx.x;
    int lo = 0, hi = NN;
    while (lo < hi) { int mid = (lo + hi) >> 1; if (batch[mid] < gi) lo = mid + 1; else hi = mid; }
    const int start = lo;
    hi = NN;
    while (lo < hi) { int mid = (lo + hi) >> 1; if (batch[mid] < gi + 1) lo = mid + 1; else hi = mid; }
    int cnt = lo - start; if (cnt < 1) cnt = 1;
    const float inv = 1.0f / (float)cnt;
    float mx0 = -INFINITY, mx1 = -INFINITY, s0 = 0.f, s1 = 0.f;
#pragma unroll
    for (int rs = 0; rs < 8; ++rs) {
        const float* p = part + ((size_t)gi * 8 + rs) * 1024;
        mx0 = fmaxf(mx0, p[t * 2]); mx1 = fmaxf(mx1, p[t * 2 + 1]);
        s0 += p[512 + t * 2]; s1 += p[512 + t * 2 + 1];
    }
    gT[(size_t)(2 * t) * 64 + gi]        = mx0;
    gT[(size_t)(2 * t + 1) * 64 + gi]    = mx1;
    gT[(size_t)(512 + 2 * t) * 64 + gi]  = s0 * inv;
    gT[(size_t)(512 + 2 * t + 1) * 64 + gi] = s1 * inv;
}

// ---------------------------------------------------------------------------
// MLP: split-K fp32 GEMM (LDS-staged) + combine
// ---------------------------------------------------------------------------
__global__ __launch_bounds__(256) void mlp_splitk(const float* __restrict__ ginT, // [K][64]
                                                  const float* __restrict__ W,    // [K][Ndim]
                                                  int Ndim,
                                                  float* __restrict__ partial) {  // [KB][64][Ndim]
    __shared__ float gsT[64][68];
    __shared__ float Ws[64][68];
    const int t = threadIdx.x;
    const int wv = t >> 6, l = t & 63;
    const int nb = blockIdx.x, kb = blockIdx.y;
    const int n0 = nb * 64;
    const int gr = t >> 2;
    const int c4 = (t & 3) * 16;
    float acc[16] = {};
#pragma unroll
    for (int sub = 0; sub < 2; ++sub) {
        const int k0 = kb * 128 + sub * 64;
        __syncthreads();
        {
            const float4* gsrc = (const float4*)(ginT + (size_t)(k0 + gr) * 64 + c4);
            float4* gd = (float4*)&gsT[gr][c4];
            gd[0] = gsrc[0]; gd[1] = gsrc[1]; gd[2] = gsrc[2]; gd[3] = gsrc[3];
            const float4* wsrc = (const float4*)(W + (size_t)(k0 + gr) * Ndim + n0 + c4);
            float4* wd = (float4*)&Ws[gr][c4];
            wd[0] = wsrc[0]; wd[1] = wsrc[1]; wd[2] = wsrc[2]; wd[3] = wsrc[3];
        }
        __syncthreads();
#pragma unroll 4
        for (int kk = 0; kk < 64; ++kk) {
            const float wval = Ws[kk][l];
            const float4* gv = (const float4*)&gsT[kk][wv * 16];
            float4 g0 = gv[0], g1 = gv[1], g2 = gv[2], g3 = gv[3];
            acc[0]  = fmaf(g0.x, wval, acc[0]);  acc[1]  = fmaf(g0.y, wval, acc[1]);
            acc[2]  = fmaf(g0.z, wval, acc[2]);  acc[3]  = fmaf(g0.w, wval, acc[3]);
            acc[4]  = fmaf(g1.x, wval, acc[4]);  acc[5]  = fmaf(g1.y, wval, acc[5]);
            acc[6]  = fmaf(g1.z, wval, acc[6]);  acc[7]  = fmaf(g1.w, wval, acc[7]);
            acc[8]  = fmaf(g2.x, wval, acc[8]);  acc[9]  = fmaf(g2.y, wval, acc[9]);
            acc[10] = fmaf(g2.z, wval, acc[10]); acc[11] = fmaf(g2.w, wval, acc[11]);
            acc[12] = fmaf(g3.x, wval, acc[12]); acc[13] = fmaf(g3.y, wval, acc[13]);
            acc[14] = fmaf(g3.z, wval, acc[14]); acc[15] = fmaf(g3.w, wval, acc[15]);
        }
    }
    float* p = partial + ((size_t)kb * 64) * Ndim;
#pragma unroll
    for (int g = 0; g < 16; ++g)
        p[(size_t)(wv * 16 + g) * Ndim + n0 + l] = acc[g];
}

__global__ __launch_bounds__(256) void mlp_combine(const float* __restrict__ partial, int nparts,
                                                   const float* __restrict__ bias, int Ndim,
                                                   float* __restrict__ outN,
                                                   float* __restrict__ outT) {
    const int idx = blockIdx.x * 256 + threadIdx.x;
    if (idx >= 64 * Ndim) return;
    const int g = idx / Ndim, n = idx - g * Ndim;
    float s = bias[n];
    for (int kb = 0; kb < nparts; ++kb)
        s += partial[((size_t)kb * 64 + g) * Ndim + n];
    const float v = fast_tanh(s);
    if (outN) outN[(size_t)g * Ndim + n] = v;
    if (outT) outT[(size_t)n * 64 + g] = v;
}

// ---------------------------------------------------------------------------
// Head: lane t covers k = t*8..t*8+7; wave butterfly reduce per class.
// ---------------------------------------------------------------------------
__global__ __launch_bounds__(64) void head_kernel(const float* __restrict__ g2,
                                                  const float* __restrict__ W,
                                                  const float* __restrict__ b,
                                                  float* __restrict__ out) {
    const int gi = blockIdx.x, t = threadIdx.x;
    const float4* gp = (const float4*)(g2 + (size_t)gi * HH + t * 8);
    float4 ga = gp[0], gb = gp[1];
    float gv[8] = {ga.x, ga.y, ga.z, ga.w, gb.x, gb.y, gb.z, gb.w};
    float logits[CC];
#pragma unroll
    for (int c = 0; c < CC; ++c) {
        float p = 0.f;
#pragma unroll
        for (int j = 0; j < 8; ++j)
            p = fmaf(gv[j], W[(t * 8 + j) * CC + c], p);
#pragma unroll
        for (int off = 32; off > 0; off >>= 1)
            p += __shfl_xor(p, off, 64);
        logits[c] = p + b[c];
    }
    if (t == 0) {
        float mx = logits[0];
#pragma unroll
        for (int c = 1; c < CC; ++c) mx = fmaxf(mx, logits[c]);
        float s = 0.f;
#pragma unroll
        for (int c = 0; c < CC; ++c) s += expf(logits[c] - mx);
        float lse = mx + logf(s);
#pragma unroll
        for (int c = 0; c < CC; ++c) out[(size_t)gi * CC + c] = logits[c] - lse;
    }
}

// ---------------------------------------------------------------------------
extern "C" void kernel_launch(void* const* d_in, const int* in_sizes, int n_in,
                              void* d_out, int out_size, void* d_ws, size_t ws_size,
                              hipStream_t stream) {
    const float* x       = (const float*)d_in[0];
    const int*   ei      = (const int*)d_in[1];
    const int*   batch   = (const int*)d_in[2];
    const float* w_root0 = (const float*)d_in[3];
    const float* w_rel0  = (const float*)d_in[4];
    const float* b0      = (const float*)d_in[5];
    const float* w_root  = (const float*)d_in[6];
    const float* w_rel   = (const float*)d_in[7];
    const float* bvec    = (const float*)d_in[8];
    const float* lin1_w  = (const float*)d_in[9];
    const float* lin1_b  = (const float*)d_in[10];
    const float* lin2_w  = (const float*)d_in[11];
    const float* lin2_b  = (const float*)d_in[12];
    const float* lin3_w  = (const float*)d_in[13];
    const float* lin3_b  = (const float*)d_in[14];
    float* out = (float*)d_out;

    char* w = (char*)d_ws;
    size_t off = 0;
    auto alloc = [&](size_t bytes) -> char* {
        char* p = w + off;
        off += (bytes + 255) & ~(size_t)255;
        return p;
    };
    unsigned short* Xa  = (unsigned short*)alloc((size_t)NN * 1024 * 2);
    unsigned short* Xb  = (unsigned short*)alloc((size_t)NN * 1024 * 2);
    unsigned short* X0  = (unsigned short*)alloc((size_t)NN * 64 * 2);
    unsigned short* WT0 = (unsigned short*)alloc(512 * 64 * 2);
    unsigned short* WTs = (unsigned short*)alloc((size_t)4 * 512 * 1024 * 2);
    int* counts   = (int*)alloc((size_t)(NN + 512) * 4);  // counts + degHist + degBump
    int* degHist  = counts + NN;
    int* degBump  = counts + NN + 256;
    int* perm     = (int*)alloc((size_t)NN * 4);
    int* pDeg     = (int*)alloc((size_t)NN * 4);
    int* iperm    = (int*)alloc((size_t)NN * 4);
    int* pRowStart= (int*)alloc((size_t)(NN + 1) * 4);
    int* pCursor  = (int*)alloc((size_t)NN * 4);
    int* pssrc    = (int*)alloc((size_t)EE * 4);
    float* gbufT  = (float*)alloc((size_t)1024 * 64 * 4);
    float* g1T    = (float*)alloc((size_t)512 * 64 * 4);
    float* g2buf  = (float*)alloc((size_t)GG * 512 * 4);
    float* mlpPart = (float*)alloc((size_t)8 * 64 * 512 * 4);
    float* part   = (float*)X0;   // pool partials alias X0 (dead after layer 0); 2 MB

    const int* esrc = ei;
    const int* edst = ei + EE;

    // prep; degree hist; parallel degree-sort (scan folded into scatter);
    // pDeg scan; direct permuted-CSR edge scatter.
    prep_all_kernel<<<4649, 256, 0, stream>>>(w_root0, w_rel0, WT0, w_root, w_rel, WTs, x, X0, counts);
    hist_kernel<<<2048, 256, 0, stream>>>(edst, counts);
    deg_hist_kernel<<<128, 256, 0, stream>>>(counts, degHist);
    deg_scatter_kernel<<<128, 256, 0, stream>>>(counts, degHist, degBump, perm, pDeg, iperm);
    scan_kernel<<<1, 1024, 0, stream>>>(pDeg, pRowStart, pCursor);
    scatter_kernel<<<2048, 256, 0, stream>>>(esrc, edst, iperm, pCursor, pssrc);

    // layer 0: F=32 -> H  (permuted CSR). Grid (256,4): N=512 = 4 bn-blocks.
    agg_kernel<<<512, 256, 0, stream>>>(X0, X0 + 32, pRowStart, pssrc, perm);
    gemm_bias_tanh<<<dim3(256, 4), 256, 0, stream>>>(X0, 64, 64, WT0, b0, Xa, 1024);

    // layers 1..4: all gemm256 (R8 config -- best timed total 572.8us)
    agg_slice_kernel<<<4096, 256, 0, stream>>>(Xa, Xa + 512, pRowStart, pssrc, perm);
    gemm256_bias_tanh<<<256, 512, 0, stream>>>(Xa, 1024, 1024, WTs + 0 * 524288, bvec + 0, Xb, 1024);
    agg_slice_kernel<<<4096, 256, 0, stream>>>(Xb, Xb + 512, pRowStart, pssrc, perm);
    gemm256_bias_tanh<<<256, 512, 0, stream>>>(Xb, 1024, 1024, WTs + 1 * 524288, bvec + 512, Xa, 1024);
    agg_slice_kernel<<<4096, 256, 0, stream>>>(Xa, Xa + 512, pRowStart, pssrc, perm);
    gemm256_bias_tanh<<<256, 512, 0, stream>>>(Xa, 1024, 1024, WTs + 2 * 524288, bvec + 1024, Xb, 1024);
    agg_slice_kernel<<<4096, 256, 0, stream>>>(Xb, Xb + 512, pRowStart, pssrc, perm);
    gemm256_bias_tanh<<<256, 512, 0, stream>>>(Xb, 1024, 1024, WTs + 3 * 524288, bvec + 1536, Xa, 1024);

    // pooling + MLP tail (LDS-staged split-K GEMMs)
    pool_partial<<<dim3(GG, 8), 256, 0, stream>>>(Xa, batch, part);
    pool_combine<<<GG, 256, 0, stream>>>(part, batch, gbufT);
    mlp_splitk<<<dim3(8, 8), 256, 0, stream>>>(gbufT, lin1_w, 512, mlpPart);
    mlp_combine<<<128, 256, 0, stream>>>(mlpPart, 8, lin1_b, 512, nullptr, g1T);
    mlp_splitk<<<dim3(8, 4), 256, 0, stream>>>(g1T, lin2_w, 512, mlpPart);
    mlp_combine<<<128, 256, 0, stream>>>(mlpPart, 4, lin2_b, 512, g2buf, nullptr);
    head_kernel<<<GG, 64, 0, stream>>>(g2buf, lin3_w, lin3_b, out);
}

// Round 12
// 563.181 us; speedup vs baseline: 1.0452x; 1.0277x over previous
//
#include <hip/hip_runtime.h>
#include <hip/hip_bf16.h>
#include <math.h>

#define NN 32768
#define EE 524288
#define FF 32
#define HH 512
#define GG 64
#define CC 10

typedef __attribute__((ext_vector_type(8))) short short8;
typedef __attribute__((ext_vector_type(4))) float floatx4;
typedef __attribute__((ext_vector_type(4))) unsigned int uintx4;

__device__ __forceinline__ float bf16_to_f32(unsigned short u) {
    union { unsigned int u; float f; } v;
    v.u = ((unsigned int)u) << 16;
    return v.f;
}
__device__ __forceinline__ unsigned short f32_to_bf16(float f) {
    union { float f; unsigned int u; } v;
    v.f = f;
    unsigned int u = v.u;
    u += 0x7FFFu + ((u >> 16) & 1u);   // round-to-nearest-even
    return (unsigned short)(u >> 16);
}
// tanh(x) = 1 - 2/(1+e^{2x});  exact at +-inf, err far below bf16 grid
__device__ __forceinline__ float fast_tanh(float x) {
    float e = __expf(2.0f * x);
    return 1.0f - 2.0f * __builtin_amdgcn_rcpf(e + 1.0f);
}

// ---------------------------------------------------------------------------
// Merged prep: LDS-tiled weight transpose + X0 cast + counts/degHist/degBump
// zero. blocks [0,8): WT0; [8,520): WTs; [520,4616): X0 cast; [4616,4649):
// zero (counts NN + degHist 256 + degBump 256 ints, contiguous).
// ---------------------------------------------------------------------------
__global__ __launch_bounds__(256) void prep_all_kernel(const float* __restrict__ wr0, const float* __restrict__ wl0,
                                unsigned short* __restrict__ WT0,
                                const float* __restrict__ wroot, const float* __restrict__ wrel,
                                unsigned short* __restrict__ WTs,
                                const float* __restrict__ x, unsigned short* __restrict__ X0,
                                int* __restrict__ counts) {
    const int b = blockIdx.x;
    const int tid = threadIdx.x;
    if (b < 520) {
        __shared__ unsigned short tile[64][65];
        const int ty = tid >> 6, tx = tid & 63;
        if (b < 8) {
            const int n0 = b * 64;
#pragma unroll
            for (int q = 0; q < 16; ++q) {
                const int k = ty * 16 + q;
                const float v = (k < 32) ? wr0[k * 512 + n0 + tx]
                                         : wl0[(k - 32) * 512 + n0 + tx];
                tile[k][tx] = f32_to_bf16(v);
            }
            __syncthreads();
#pragma unroll
            for (int q = 0; q < 16; ++q) {
                const int n = n0 + ty * 16 + q;
                WT0[n * 64 + tx] = tile[tx][ty * 16 + q];
            }
        } else {
            const int bb = b - 8;          // 0..511
            const int l = bb >> 7;         // layer
            const int r = bb & 127;        // 16 ktile x 8 ntile
            const int k0 = (r >> 3) * 64;  // multiple of 64 -> never straddles 512
            const int n0 = (r & 7) * 64;
            const float* Wl = (k0 < 512) ? wroot + (size_t)l * 262144
                                         : wrel + (size_t)l * 262144;
            const int kb = (k0 < 512) ? k0 : k0 - 512;
#pragma unroll
            for (int q = 0; q < 16; ++q) {
                const int kk = ty * 16 + q;
                tile[kk][tx] = f32_to_bf16(Wl[(size_t)(kb + kk) * 512 + n0 + tx]);
            }
            __syncthreads();
#pragma unroll
            for (int q = 0; q < 16; ++q) {
                const int n = n0 + ty * 16 + q;
                WTs[(size_t)l * 524288 + (size_t)n * 1024 + k0 + tx] = tile[tx][ty * 16 + q];
            }
        }
    } else if (b < 4616) {
        const int t = (b - 520) * 256 + tid; // NN*32
        const int i = t >> 5, c = t & 31;
        X0[(size_t)i * 64 + c] = f32_to_bf16(x[t]);
    } else {
        const int t4 = (b - 4616) * 256 + tid;   // counts+degHist+degBump = (NN+512)/4 = 8320 int4
        if (t4 < 8320) {
            int4 z; z.x = 0; z.y = 0; z.z = 0; z.w = 0;
            ((int4*)counts)[t4] = z;
        }
    }
}

// ---------------------------------------------------------------------------
// hist: per-dst degree counts (counts zeroed by prep).
// ---------------------------------------------------------------------------
__global__ void hist_kernel(const int* __restrict__ dst, int* __restrict__ counts) {
    int e = blockIdx.x * blockDim.x + threadIdx.x;
    if (e < EE) atomicAdd(&counts[dst[e]], 1);
}

// degree histogram (bin = 255-deg -> descending sort), LDS pre-aggregated,
// 128 blocks.
__global__ __launch_bounds__(256) void deg_hist_kernel(const int* __restrict__ counts,
                                                       int* __restrict__ degHist) {
    __shared__ int lh[256];
    lh[threadIdx.x] = 0;
    __syncthreads();
    int i = blockIdx.x * 256 + threadIdx.x;
    int d = counts[i]; if (d > 255) d = 255;
    atomicAdd(&lh[255 - d], 1);
    __syncthreads();
    int v = lh[threadIdx.x];
    if (v) atomicAdd(&degHist[threadIdx.x], v);
}

// deg_scatter v2: folds deg_scan in -- each block recomputes the 256-bin
// exclusive scan of degHist in LDS and uses zeroed degBump[] for cross-block
// bin cursoring.
__global__ __launch_bounds__(256) void deg_scatter_kernel(const int* __restrict__ counts,
                                                          const int* __restrict__ degHist,
                                                          int* __restrict__ degBump,
                                                          int* __restrict__ perm,
                                                          int* __restrict__ pDeg,
                                                          int* __restrict__ iperm) {
    __shared__ int lh[256];
    __shared__ int sh[256];
    __shared__ int base[256];
    const int t = threadIdx.x;
    lh[t] = 0;
    const int own = degHist[t];
    sh[t] = own;
    __syncthreads();
    for (int off = 1; off < 256; off <<= 1) {
        int v = (t >= off) ? sh[t - off] : 0;
        __syncthreads();
        sh[t] += v;
        __syncthreads();
    }
    const int excl = sh[t] - own;   // exclusive prefix of bin t
    int i = blockIdx.x * 256 + t;
    int dtrue = counts[i];
    int d = dtrue > 255 ? 255 : dtrue;
    int bin = 255 - d;
    int lr = atomicAdd(&lh[bin], 1);      // local rank within (block, bin)
    __syncthreads();
    int c = lh[t];
    if (c) base[t] = excl + atomicAdd(&degBump[t], c);
    __syncthreads();
    int p = base[bin] + lr;
    perm[p] = i;
    pDeg[p] = dtrue;
    iperm[i] = p;
}
// scan pDeg (permuted order) -> pRowStart, pCursor (1024thr x 32/thread)
__global__ __launch_bounds__(1024) void scan_kernel(const int* __restrict__ pDeg,
                                                    int* __restrict__ pRowStart,
                                                    int* __restrict__ pCursor) {
    __shared__ int part[1024];
    const int t = threadIdx.x;
    const int base = t * 32;
    int local[32];
    const int4* cp = (const int4*)(pDeg + base);
    int s = 0;
#pragma unroll
    for (int ii = 0; ii < 8; ++ii) {
        int4 v = cp[ii];
        local[ii * 4 + 0] = v.x; local[ii * 4 + 1] = v.y;
        local[ii * 4 + 2] = v.z; local[ii * 4 + 3] = v.w;
        s += v.x + v.y + v.z + v.w;
    }
    part[t] = s;
    __syncthreads();
    for (int off = 1; off < 1024; off <<= 1) {
        int v = (t >= off) ? part[t - off] : 0;
        __syncthreads();
        part[t] += v;
        __syncthreads();
    }
    int run = part[t] - s;
#pragma unroll
    for (int i = 0; i < 32; ++i) {
        pRowStart[base + i] = run;
        pCursor[base + i] = run;
        run += local[i];
    }
    if (t == 1023) pRowStart[NN] = run;
}

// ---------------------------------------------------------------------------
// scatter: edges go DIRECTLY into permuted CSR (no ssrc / edge_copy).
// ---------------------------------------------------------------------------
__global__ void scatter_kernel(const int* __restrict__ src, const int* __restrict__ dst,
                               const int* __restrict__ iperm,
                               int* __restrict__ pCursor, int* __restrict__ pssrc) {
    int e = blockIdx.x * blockDim.x + threadIdx.x;
    if (e < EE) {
        int p = iperm[dst[e]];
        int q = atomicAdd(&pCursor[p], 1);
        pssrc[q] = src[e];
    }
}

// ---------------------------------------------------------------------------
__device__ __forceinline__ void acc8(float* a, uint4 d) {
    a[0] += bf16_to_f32((unsigned short)(d.x & 0xFFFFu));
    a[1] += bf16_to_f32((unsigned short)(d.x >> 16));
    a[2] += bf16_to_f32((unsigned short)(d.y & 0xFFFFu));
    a[3] += bf16_to_f32((unsigned short)(d.y >> 16));
    a[4] += bf16_to_f32((unsigned short)(d.z & 0xFFFFu));
    a[5] += bf16_to_f32((unsigned short)(d.z >> 16));
    a[6] += bf16_to_f32((unsigned short)(d.w & 0xFFFFu));
    a[7] += bf16_to_f32((unsigned short)(d.w >> 16));
}
__device__ __forceinline__ void acc8v(float* a, uintx4 d) {
    a[0] += bf16_to_f32((unsigned short)(d[0] & 0xFFFFu));
    a[1] += bf16_to_f32((unsigned short)(d[0] >> 16));
    a[2] += bf16_to_f32((unsigned short)(d[1] & 0xFFFFu));
    a[3] += bf16_to_f32((unsigned short)(d[1] >> 16));
    a[4] += bf16_to_f32((unsigned short)(d[2] & 0xFFFFu));
    a[5] += bf16_to_f32((unsigned short)(d[2] >> 16));
    a[6] += bf16_to_f32((unsigned short)(d[3] & 0xFFFFu));
    a[7] += bf16_to_f32((unsigned short)(d[3] >> 16));
}

// Layer-0 agg (cols=32), permuted CSR: 16 nodes/wave x 4 lanes/node.
__global__ __launch_bounds__(256) void agg_kernel(const unsigned short* __restrict__ Xh,
                                                  unsigned short* __restrict__ Xagg,
                                                  const int* __restrict__ pRowStart,
                                                  const int* __restrict__ pssrc,
                                                  const int* __restrict__ perm) {
    const int p = blockIdx.x * 64 + (threadIdx.x >> 2);
    const int lc = threadIdx.x & 3;
    const int node = perm[p];
    const int s = pRowStart[p];
    const int e = pRowStart[p + 1];
    float a[8] = {0.f, 0.f, 0.f, 0.f, 0.f, 0.f, 0.f, 0.f};
    const unsigned short* base = Xh + lc * 8;
    int i = s;
    for (; i + 4 <= e; i += 4) {
        int j0 = pssrc[i], j1 = pssrc[i + 1], j2 = pssrc[i + 2], j3 = pssrc[i + 3];
        uint4 d0 = *(const uint4*)(base + (size_t)j0 * 64);
        uint4 d1 = *(const uint4*)(base + (size_t)j1 * 64);
        uint4 d2 = *(const uint4*)(base + (size_t)j2 * 64);
        uint4 d3 = *(const uint4*)(base + (size_t)j3 * 64);
        acc8(a, d0); acc8(a, d1); acc8(a, d2); acc8(a, d3);
    }
    for (; i < e; ++i) {
        int j = pssrc[i];
        uint4 d = *(const uint4*)(base + (size_t)j * 64);
        acc8(a, d);
    }
    unsigned short* out = Xagg + (size_t)node * 64 + lc * 8;
#pragma unroll
    for (int c = 0; c < 8; ++c) out[c] = f32_to_bf16(a[c]);
}

// ---------------------------------------------------------------------------
// Column-sliced XCD-affine agg v6 (proven config: ~47us, L2-request-rate
// bound; depth-16 asm pipeline; plain L2-cached accesses).
// ---------------------------------------------------------------------------
#define GLOAD(dreg, voff) \
    asm volatile("buffer_load_dwordx4 %0, %1, %2, 0 offen" \
                 : "=v"(dreg) : "v"(voff), "s"(srsrc))

__global__ __launch_bounds__(256, 3) void agg_slice_kernel(const unsigned short* __restrict__ Xh,
                                                           unsigned short* __restrict__ Xagg,
                                                           const int* __restrict__ pRowStart,
                                                           const int* __restrict__ pssrc,
                                                           const int* __restrict__ perm) {
    const int slice = blockIdx.x & 7;
    const int pair = blockIdx.x >> 3;          // 0..511
    const int wv = threadIdx.x >> 6;
    const int lane = threadIdx.x & 63;
    const int ln = lane >> 3;
    const int lc = lane & 7;
    const int colOff = slice * 64 + lc * 8;
    const unsigned short* base = Xh + colOff;     // tail path (compiler loads)
    uintx4 srsrc;
    {
        union { const unsigned short* p; unsigned int u[2]; } ba;
        ba.p = Xh + slice * 64;
        srsrc[0] = ba.u[0];
        srsrc[1] = ba.u[1] & 0xFFFFu;   // stride = 0
        srsrc[2] = 0xFFFFFFFFu;         // num_records: bounds check disabled
        srsrc[3] = 0x00020000u;         // raw untyped dword
    }
    const unsigned int lcoff = (unsigned int)(lc << 4);
#pragma unroll
    for (int half = 0; half < 2; ++half) {
        const int nb = half ? (1023 - pair) : pair;
        const int p = nb * 32 + wv * 8 + ln;
        const int node = perm[p];
        const int s = pRowStart[p];
        const int e = pRowStart[p + 1];
        float a[8] = {0.f, 0.f, 0.f, 0.f, 0.f, 0.f, 0.f, 0.f};
        int i = s;
        for (; i + 16 <= e; i += 16) {
            unsigned int vo[16];
#pragma unroll
            for (int u = 0; u < 16; ++u)
                vo[u] = (((unsigned int)pssrc[i + u]) << 11) | lcoff;
            uintx4 d0, d1, d2, d3, d4, d5, d6, d7, d8, d9, d10, d11, d12, d13, d14, d15;
            __builtin_amdgcn_sched_barrier(0);
            GLOAD(d0, vo[0]);   GLOAD(d1, vo[1]);   GLOAD(d2, vo[2]);   GLOAD(d3, vo[3]);
            GLOAD(d4, vo[4]);   GLOAD(d5, vo[5]);   GLOAD(d6, vo[6]);   GLOAD(d7, vo[7]);
            GLOAD(d8, vo[8]);   GLOAD(d9, vo[9]);   GLOAD(d10, vo[10]); GLOAD(d11, vo[11]);
            GLOAD(d12, vo[12]); GLOAD(d13, vo[13]); GLOAD(d14, vo[14]); GLOAD(d15, vo[15]);
            asm volatile("s_waitcnt vmcnt(8)" ::: "memory");
            __builtin_amdgcn_sched_barrier(0);
            acc8v(a, d0); acc8v(a, d1); acc8v(a, d2); acc8v(a, d3);
            acc8v(a, d4); acc8v(a, d5); acc8v(a, d6); acc8v(a, d7);
            asm volatile("s_waitcnt vmcnt(0)" ::: "memory");
            __builtin_amdgcn_sched_barrier(0);
            acc8v(a, d8);  acc8v(a, d9);  acc8v(a, d10); acc8v(a, d11);
            acc8v(a, d12); acc8v(a, d13); acc8v(a, d14); acc8v(a, d15);
        }
        if (e - i >= 8) {
            unsigned int vo[8];
#pragma unroll
            for (int u = 0; u < 8; ++u)
                vo[u] = (((unsigned int)pssrc[i + u]) << 11) | lcoff;
            uintx4 d0, d1, d2, d3, d4, d5, d6, d7;
            __builtin_amdgcn_sched_barrier(0);
            GLOAD(d0, vo[0]); GLOAD(d1, vo[1]); GLOAD(d2, vo[2]); GLOAD(d3, vo[3]);
            GLOAD(d4, vo[4]); GLOAD(d5, vo[5]); GLOAD(d6, vo[6]); GLOAD(d7, vo[7]);
            asm volatile("s_waitcnt vmcnt(4)" ::: "memory");
            __builtin_amdgcn_sched_barrier(0);
            acc8v(a, d0); acc8v(a, d1); acc8v(a, d2); acc8v(a, d3);
            asm volatile("s_waitcnt vmcnt(0)" ::: "memory");
            __builtin_amdgcn_sched_barrier(0);
            acc8v(a, d4); acc8v(a, d5); acc8v(a, d6); acc8v(a, d7);
            i += 8;
        }
        for (; i + 4 <= e; i += 4) {
            int j0 = pssrc[i], j1 = pssrc[i + 1], j2 = pssrc[i + 2], j3 = pssrc[i + 3];
            uint4 e0 = *(const uint4*)(base + (size_t)j0 * 1024);
            uint4 e1 = *(const uint4*)(base + (size_t)j1 * 1024);
            uint4 e2 = *(const uint4*)(base + (size_t)j2 * 1024);
            uint4 e3 = *(const uint4*)(base + (size_t)j3 * 1024);
            acc8(a, e0); acc8(a, e1); acc8(a, e2); acc8(a, e3);
        }
        for (; i < e; ++i) {
            int j = pssrc[i];
            uint4 d = *(const uint4*)(base + (size_t)j * 1024);
            acc8(a, d);
        }
        unsigned short* out = Xagg + (size_t)node * 1024 + colOff;
#pragma unroll
        for (int c = 0; c < 8; ++c) out[c] = f32_to_bf16(a[c]);
    }
}

// ---------------------------------------------------------------------------
// bf16 MFMA GEMM 128x128: BK=64, XOR-swizzled LDS. Used for layer 0 (K=64).
// ---------------------------------------------------------------------------
__global__ __launch_bounds__(256, 4) void gemm_bias_tanh(const unsigned short* __restrict__ Xin,
                                                         int ldin, int K,
                                                         const unsigned short* __restrict__ WT,
                                                         const float* __restrict__ bias,
                                                         unsigned short* __restrict__ Xout,
                                                         int ldout) {
    __shared__ __align__(16) unsigned short As[128 * 64];
    __shared__ __align__(16) unsigned short Bs[128 * 64];
    const int tid = threadIdx.x;
    const int lane = tid & 63;
    const int wave = tid >> 6;
    const int wm = wave >> 1, wn = wave & 1;
    const int bm = blockIdx.x, bn = blockIdx.y;

    floatx4 acc[4][4] = {};

    const int lrow = lane >> 3;
    const int schunk = (lane & 7) ^ (lrow & 7);
    const unsigned short* Abase = Xin + (size_t)(bm * 128) * ldin;
    const unsigned short* Bbase = WT + (size_t)(bn * 128) * K;
    const int m = lane & 15;
    const int quad = lane >> 4;

    for (int k0 = 0; k0 < K; k0 += 64) {
        __syncthreads();
#pragma unroll
        for (int q = 0; q < 4; ++q) {
            const int rr = q * 32 + wave * 8;
            const int row = rr + lrow;
            const unsigned short* sa = Abase + (size_t)row * ldin + (k0 + schunk * 8);
            const unsigned short* sb = Bbase + (size_t)row * K + (k0 + schunk * 8);
            __builtin_amdgcn_global_load_lds(
                (const __attribute__((address_space(1))) void*)sa,
                (__attribute__((address_space(3))) void*)(&As[rr * 64]), 16, 0, 0);
            __builtin_amdgcn_global_load_lds(
                (const __attribute__((address_space(1))) void*)sb,
                (__attribute__((address_space(3))) void*)(&Bs[rr * 64]), 16, 0, 0);
        }
        __syncthreads();
#pragma unroll
        for (int half = 0; half < 2; ++half) {
            short8 af[4], bfr[4];
#pragma unroll
            for (int t = 0; t < 4; ++t) {
                const int row = wm * 64 + t * 16 + m;
                const int chunk = (half * 4 + quad) ^ (row & 7);
                af[t] = *(const short8*)&As[row * 64 + chunk * 8];
            }
#pragma unroll
            for (int t = 0; t < 4; ++t) {
                const int row = wn * 64 + t * 16 + m;
                const int chunk = (half * 4 + quad) ^ (row & 7);
                bfr[t] = *(const short8*)&Bs[row * 64 + chunk * 8];
            }
#pragma unroll
            for (int mt = 0; mt < 4; ++mt)
#pragma unroll
                for (int nt = 0; nt < 4; ++nt)
                    acc[mt][nt] = __builtin_amdgcn_mfma_f32_16x16x32_bf16(af[mt], bfr[nt],
                                                                          acc[mt][nt], 0, 0, 0);
        }
    }

    const int row0 = bm * 128 + wm * 64;
    const int col0 = bn * 128 + wn * 64;
#pragma unroll
    for (int mt = 0; mt < 4; ++mt) {
#pragma unroll
        for (int nt = 0; nt < 4; ++nt) {
            const int col = col0 + nt * 16 + m;
            const float bv = bias[col];
#pragma unroll
            for (int r = 0; r < 4; ++r) {
                const int row = row0 + mt * 16 + quad * 4 + r;
                float v = fast_tanh(acc[mt][nt][r] + bv);
                Xout[(size_t)row * ldout + col] = f32_to_bf16(v);
            }
        }
    }
}

// ---------------------------------------------------------------------------
// 256x256 bf16 MFMA GEMM v3: guide's MINIMAL 2-phase template (m230/m248).
// Depth-1 double-buffer: stage tile kt+1 into buf[cur^1] while computing
// buf[cur] -- race-free BY CONSTRUCTION (write-buffer != read-buffer; the
// end-of-iter __syncthreads drains vmcnt so the stage lands before buf^1 is
// read, and all buf[cur] reads finish before it's overwritten next iter).
// ONE barrier per K-tile (16/block) vs v2's 8 (128/block). No inline asm:
// compiler emits fine-grained lgkmcnt for ds_read->MFMA (guide G7), and
// __syncthreads' implicit vmcnt(0) is the per-tile drain the template takes.
// A-frags read in two halves (reuse regs) to keep live set ~210 VGPR.
// ---------------------------------------------------------------------------
__device__ __forceinline__ void stage_half(const unsigned short* __restrict__ gsrc0,
                                           int ldg, unsigned short* ldsHalf,
                                           int w, int lane) {
#pragma unroll
    for (int q = 0; q < 2; ++q) {
        const int rb = q * 64 + w * 8;                       // wave-uniform row block (8 rows)
        const unsigned short* src = gsrc0 + (size_t)(rb + (lane >> 3)) * ldg
                                    + ((lane & 7) ^ (lane >> 3)) * 8;   // pre-swizzled source
        __builtin_amdgcn_global_load_lds(
            (const __attribute__((address_space(1))) void*)src,
            (__attribute__((address_space(3))) void*)(ldsHalf + rb * 64), 16, 0, 0);
    }
}

__global__ __launch_bounds__(512, 2) void gemm256_bias_tanh(
    const unsigned short* __restrict__ Xin, int ldin, int K,
    const unsigned short* __restrict__ WT, const float* __restrict__ bias,
    unsigned short* __restrict__ Xout, int ldout) {
    __shared__ __align__(16) unsigned short As[2][256 * 64];   // 64KB
    __shared__ __align__(16) unsigned short Bs[2][256 * 64];   // 64KB
    const int tid = threadIdx.x;
    const int lane = tid & 63;
    const int w = tid >> 6;                 // 0..7
    const int wm = w >> 2, wn = w & 3;      // 2 x 4 wave grid
    const int m = lane & 15, quad = lane >> 4;
    // XCD-chunked swizzle: A-panel sharers co-resident on one XCD.
    const int id = (int)blockIdx.x;
    const int bm = (id & 7) * 16 + (id >> 4);
    const int bn = (id >> 3) & 1;
    const int NT = K >> 6;

    const unsigned short* Abase = Xin + (size_t)(bm * 256) * ldin;
    const unsigned short* Bbase = WT + (size_t)(bn * 256) * K;

    floatx4 acc[8][4] = {};

    // stage one full 256-row tile (A+B) of K-tile kt_ into buffer buf:
    // 8 global_load_lds per thread.
#define STG_T(buf, kt_) do { \
        stage_half(Bbase + (kt_) * 64, K, &Bs[buf][0], w, lane); \
        stage_half(Bbase + (size_t)128 * K + (kt_) * 64, K, &Bs[buf][128 * 64], w, lane); \
        stage_half(Abase + (kt_) * 64, ldin, &As[buf][0], w, lane); \
        stage_half(Abase + (size_t)128 * ldin + (kt_) * 64, ldin, &As[buf][128 * 64], w, lane); \
    } while (0)

    // prologue: tile 0 -> buf 0; __syncthreads drains vmcnt -> landed.
    STG_T(0, 0);
    __syncthreads();

    for (int kt = 0; kt < NT; ++kt) {
        const int cur = kt & 1;
        if (kt + 1 < NT) STG_T(cur ^ 1, kt + 1);   // prefetch into OTHER buffer
        const unsigned short* Ac = &As[cur][0];
        const unsigned short* Bc = &Bs[cur][0];
        short8 bfr[8], afr[8];
        // B fragments (whole 64-col slice, both k-halves)
#pragma unroll
        for (int nf = 0; nf < 4; ++nf)
#pragma unroll
            for (int ks = 0; ks < 2; ++ks) {
                const int col = wn * 64 + nf * 16 + m;
                const int chunk = (ks * 4 + quad) ^ (col & 7);
                bfr[nf * 2 + ks] = *(const short8*)&Bc[col * 64 + chunk * 8];
            }
        // A low half (rows wm*128 + 0..63)
#pragma unroll
        for (int t = 0; t < 4; ++t)
#pragma unroll
            for (int ks = 0; ks < 2; ++ks) {
                const int row = wm * 128 + t * 16 + m;
                const int chunk = (ks * 4 + quad) ^ (row & 7);
                afr[t * 2 + ks] = *(const short8*)&Ac[row * 64 + chunk * 8];
            }
#pragma unroll
        for (int t = 0; t < 4; ++t)
#pragma unroll
            for (int u = 0; u < 4; ++u)
#pragma unroll
                for (int ks = 0; ks < 2; ++ks)
                    acc[t][u] = __builtin_amdgcn_mfma_f32_16x16x32_bf16(
                        afr[t * 2 + ks], bfr[u * 2 + ks], acc[t][u], 0, 0, 0);
        // A high half (rows wm*128 + 64..127), reuse afr registers
#pragma unroll
        for (int t = 0; t < 4; ++t)
#pragma unroll
            for (int ks = 0; ks < 2; ++ks) {
                const int row = wm * 128 + (4 + t) * 16 + m;
                const int chunk = (ks * 4 + quad) ^ (row & 7);
                afr[t * 2 + ks] = *(const short8*)&Ac[row * 64 + chunk * 8];
            }
#pragma unroll
        for (int t = 0; t < 4; ++t)
#pragma unroll
            for (int u = 0; u < 4; ++u)
#pragma unroll
                for (int ks = 0; ks < 2; ++ks)
                    acc[4 + t][u] = __builtin_amdgcn_mfma_f32_16x16x32_bf16(
                        afr[t * 2 + ks], bfr[u * 2 + ks], acc[4 + t][u], 0, 0, 0);
        // single per-tile barrier: drains vmcnt (stage kt+1 landed) and lgkm
        // (all reads of buf[cur] done) -> next iter may read buf^1 and
        // overwrite buf[cur].
        __syncthreads();
    }
#undef STG_T

    const int row0 = bm * 256 + wm * 128;
    const int col0 = bn * 256 + wn * 64;
#pragma unroll
    for (int mf = 0; mf < 8; ++mf) {
#pragma unroll
        for (int nf = 0; nf < 4; ++nf) {
            const int col = col0 + nf * 16 + m;
            const float bv = bias[col];
#pragma unroll
            for (int r = 0; r < 4; ++r) {
                const int row = row0 + mf * 16 + quad * 4 + r;
                float v = fast_tanh(acc[mf][nf][r] + bv);
                Xout[(size_t)row * ldout + col] = f32_to_bf16(v);
            }
        }
    }
}

// ---------------------------------------------------------------------------
// Pooling: 2-stage (8 row-slices); stage 2 writes TRANSPOSED gbufT[f][graph].
// ---------------------------------------------------------------------------
__global__ __launch_bounds__(256) void pool_partial(const unsigned short* __restrict__ h,
                                                    const int* __restrict__ batch,
                                                    float* __restrict__ part) {
    const int gi = blockIdx.x, rs = blockIdx.y, t = threadIdx.x;
    int lo = 0, hi = NN;
    while (lo < hi) { int mid = (lo + hi) >> 1; if (batch[mid] < gi) lo = mid + 1; else hi = mid; }
    const int start = lo;
    hi = NN;
    while (lo < hi) { int mid = (lo + hi) >> 1; if (batch[mid] < gi + 1) lo = mid + 1; else hi = mid; }
    const int end = lo;
    const int len = end - start;
    const int q = (len + 7) >> 3;
    int r0 = start + rs * q;
    int r1 = r0 + q; if (r1 > end) r1 = end; if (r0 > end) r0 = end;
    float mx0 = -INFINITY, mx1 = -INFINITY, s0 = 0.f, s1 = 0.f;
    int i = r0;
    for (; i + 2 <= r1; i += 2) {
        unsigned int d0 = *(const unsigned int*)(h + (size_t)i * 1024 + t * 2);
        unsigned int d1 = *(const unsigned int*)(h + (size_t)(i + 1) * 1024 + t * 2);
        float v0 = bf16_to_f32((unsigned short)(d0 & 0xFFFFu));
        float v1 = bf16_to_f32((unsigned short)(d0 >> 16));
        float w0 = bf16_to_f32((unsigned short)(d1 & 0xFFFFu));
        float w1 = bf16_to_f32((unsigned short)(d1 >> 16));
        mx0 = fmaxf(mx0, fmaxf(v0, w0)); mx1 = fmaxf(mx1, fmaxf(v1, w1));
        s0 += v0 + w0; s1 += v1 + w1;
    }
    for (; i < r1; ++i) {
        unsigned int d0 = *(const unsigned int*)(h + (size_t)i * 1024 + t * 2);
        float v0 = bf16_to_f32((unsigned short)(d0 & 0xFFFFu));
        float v1 = bf16_to_f32((unsigned short)(d0 >> 16));
        mx0 = fmaxf(mx0, v0); mx1 = fmaxf(mx1, v1);
        s0 += v0; s1 += v1;
    }
    float* p = part + ((size_t)gi * 8 + rs) * 1024;
    p[t * 2] = mx0; p[t * 2 + 1] = mx1;
    p[512 + t * 2] = s0; p[512 + t * 2 + 1] = s1;
}

__global__ __launch_bounds__(256) void pool_combine(const float* __restrict__ part,
                                                    const int* __restrict__ batch,
                                                    float* __restrict__ gT) {
    const int gi = blockIdx.x, t = threadIdx.x;
    int lo = 0, hi = NN;
    while (lo < hi) { int mid = (lo + hi) >> 1; if (batch[mid] < gi) lo = mid + 1; else hi = mid; }
    const int start = lo;
    hi = NN;
    while (lo < hi) { int mid = (lo + hi) >> 1; if (batch[mid] < gi + 1) lo = mid + 1; else hi = mid; }
    int cnt = lo - start; if (cnt < 1) cnt = 1;
    const float inv = 1.0f / (float)cnt;
    float mx0 = -INFINITY, mx1 = -INFINITY, s0 = 0.f, s1 = 0.f;
#pragma unroll
    for (int rs = 0; rs < 8; ++rs) {
        const float* p = part + ((size_t)gi * 8 + rs) * 1024;
        mx0 = fmaxf(mx0, p[t * 2]); mx1 = fmaxf(mx1, p[t * 2 + 1]);
        s0 += p[512 + t * 2]; s1 += p[512 + t * 2 + 1];
    }
    gT[(size_t)(2 * t) * 64 + gi]        = mx0;
    gT[(size_t)(2 * t + 1) * 64 + gi]    = mx1;
    gT[(size_t)(512 + 2 * t) * 64 + gi]  = s0 * inv;
    gT[(size_t)(512 + 2 * t + 1) * 64 + gi] = s1 * inv;
}

// ---------------------------------------------------------------------------
// MLP: split-K fp32 GEMM (LDS-staged) + combine
// ---------------------------------------------------------------------------
__global__ __launch_bounds__(256) void mlp_splitk(const float* __restrict__ ginT, // [K][64]
                                                  const float* __restrict__ W,    // [K][Ndim]
                                                  int Ndim,
                                                  float* __restrict__ partial) {  // [KB][64][Ndim]
    __shared__ float gsT[64][68];
    __shared__ float Ws[64][68];
    const int t = threadIdx.x;
    const int wv = t >> 6, l = t & 63;
    const int nb = blockIdx.x, kb = blockIdx.y;
    const int n0 = nb * 64;
    const int gr = t >> 2;
    const int c4 = (t & 3) * 16;
    float acc[16] = {};
#pragma unroll
    for (int sub = 0; sub < 2; ++sub) {
        const int k0 = kb * 128 + sub * 64;
        __syncthreads();
        {
            const float4* gsrc = (const float4*)(ginT + (size_t)(k0 + gr) * 64 + c4);
            float4* gd = (float4*)&gsT[gr][c4];
            gd[0] = gsrc[0]; gd[1] = gsrc[1]; gd[2] = gsrc[2]; gd[3] = gsrc[3];
            const float4* wsrc = (const float4*)(W + (size_t)(k0 + gr) * Ndim + n0 + c4);
            float4* wd = (float4*)&Ws[gr][c4];
            wd[0] = wsrc[0]; wd[1] = wsrc[1]; wd[2] = wsrc[2]; wd[3] = wsrc[3];
        }
        __syncthreads();
#pragma unroll 4
        for (int kk = 0; kk < 64; ++kk) {
            const float wval = Ws[kk][l];
            const float4* gv = (const float4*)&gsT[kk][wv * 16];
            float4 g0 = gv[0], g1 = gv[1], g2 = gv[2], g3 = gv[3];
            acc[0]  = fmaf(g0.x, wval, acc[0]);  acc[1]  = fmaf(g0.y, wval, acc[1]);
            acc[2]  = fmaf(g0.z, wval, acc[2]);  acc[3]  = fmaf(g0.w, wval, acc[3]);
            acc[4]  = fmaf(g1.x, wval, acc[4]);  acc[5]  = fmaf(g1.y, wval, acc[5]);
            acc[6]  = fmaf(g1.z, wval, acc[6]);  acc[7]  = fmaf(g1.w, wval, acc[7]);
            acc[8]  = fmaf(g2.x, wval, acc[8]);  acc[9]  = fmaf(g2.y, wval, acc[9]);
            acc[10] = fmaf(g2.z, wval, acc[10]); acc[11] = fmaf(g2.w, wval, acc[11]);
            acc[12] = fmaf(g3.x, wval, acc[12]); acc[13] = fmaf(g3.y, wval, acc[13]);
            acc[14] = fmaf(g3.z, wval, acc[14]); acc[15] = fmaf(g3.w, wval, acc[15]);
        }
    }
    float* p = partial + ((size_t)kb * 64) * Ndim;
#pragma unroll
    for (int g = 0; g < 16; ++g)
        p[(size_t)(wv * 16 + g) * Ndim + n0 + l] = acc[g];
}

__global__ __launch_bounds__(256) void mlp_combine(const float* __restrict__ partial, int nparts,
                                                   const float* __restrict__ bias, int Ndim,
                                                   float* __restrict__ outN,
                                                   float* __restrict__ outT) {
    const int idx = blockIdx.x * 256 + threadIdx.x;
    if (idx >= 64 * Ndim) return;
    const int g = idx / Ndim, n = idx - g * Ndim;
    float s = bias[n];
    for (int kb = 0; kb < nparts; ++kb)
        s += partial[((size_t)kb * 64 + g) * Ndim + n];
    const float v = fast_tanh(s);
    if (outN) outN[(size_t)g * Ndim + n] = v;
    if (outT) outT[(size_t)n * 64 + g] = v;
}

// ---------------------------------------------------------------------------
// Head: lane t covers k = t*8..t*8+7; wave butterfly reduce per class.
// ---------------------------------------------------------------------------
__global__ __launch_bounds__(64) void head_kernel(const float* __restrict__ g2,
                                                  const float* __restrict__ W,
                                                  const float* __restrict__ b,
                                                  float* __restrict__ out) {
    const int gi = blockIdx.x, t = threadIdx.x;
    const float4* gp = (const float4*)(g2 + (size_t)gi * HH + t * 8);
    float4 ga = gp[0], gb = gp[1];
    float gv[8] = {ga.x, ga.y, ga.z, ga.w, gb.x, gb.y, gb.z, gb.w};
    float logits[CC];
#pragma unroll
    for (int c = 0; c < CC; ++c) {
        float p = 0.f;
#pragma unroll
        for (int j = 0; j < 8; ++j)
            p = fmaf(gv[j], W[(t * 8 + j) * CC + c], p);
#pragma unroll
        for (int off = 32; off > 0; off >>= 1)
            p += __shfl_xor(p, off, 64);
        logits[c] = p + b[c];
    }
    if (t == 0) {
        float mx = logits[0];
#pragma unroll
        for (int c = 1; c < CC; ++c) mx = fmaxf(mx, logits[c]);
        float s = 0.f;
#pragma unroll
        for (int c = 0; c < CC; ++c) s += expf(logits[c] - mx);
        float lse = mx + logf(s);
#pragma unroll
        for (int c = 0; c < CC; ++c) out[(size_t)gi * CC + c] = logits[c] - lse;
    }
}

// ---------------------------------------------------------------------------
extern "C" void kernel_launch(void* const* d_in, const int* in_sizes, int n_in,
                              void* d_out, int out_size, void* d_ws, size_t ws_size,
                              hipStream_t stream) {
    const float* x       = (const float*)d_in[0];
    const int*   ei      = (const int*)d_in[1];
    const int*   batch   = (const int*)d_in[2];
    const float* w_root0 = (const float*)d_in[3];
    const float* w_rel0  = (const float*)d_in[4];
    const float* b0      = (const float*)d_in[5];
    const float* w_root  = (const float*)d_in[6];
    const float* w_rel   = (const float*)d_in[7];
    const float* bvec    = (const float*)d_in[8];
    const float* lin1_w  = (const float*)d_in[9];
    const float* lin1_b  = (const float*)d_in[10];
    const float* lin2_w  = (const float*)d_in[11];
    const float* lin2_b  = (const float*)d_in[12];
    const float* lin3_w  = (const float*)d_in[13];
    const float* lin3_b  = (const float*)d_in[14];
    float* out = (float*)d_out;

    char* w = (char*)d_ws;
    size_t off = 0;
    auto alloc = [&](size_t bytes) -> char* {
        char* p = w + off;
        off += (bytes + 255) & ~(size_t)255;
        return p;
    };
    unsigned short* Xa  = (unsigned short*)alloc((size_t)NN * 1024 * 2);
    unsigned short* Xb  = (unsigned short*)alloc((size_t)NN * 1024 * 2);
    unsigned short* X0  = (unsigned short*)alloc((size_t)NN * 64 * 2);
    unsigned short* WT0 = (unsigned short*)alloc(512 * 64 * 2);
    unsigned short* WTs = (unsigned short*)alloc((size_t)4 * 512 * 1024 * 2);
    int* counts   = (int*)alloc((size_t)(NN + 512) * 4);  // counts + degHist + degBump
    int* degHist  = counts + NN;
    int* degBump  = counts + NN + 256;
    int* perm     = (int*)alloc((size_t)NN * 4);
    int* pDeg     = (int*)alloc((size_t)NN * 4);
    int* iperm    = (int*)alloc((size_t)NN * 4);
    int* pRowStart= (int*)alloc((size_t)(NN + 1) * 4);
    int* pCursor  = (int*)alloc((size_t)NN * 4);
    int* pssrc    = (int*)alloc((size_t)EE * 4);
    float* gbufT  = (float*)alloc((size_t)1024 * 64 * 4);
    float* g1T    = (float*)alloc((size_t)512 * 64 * 4);
    float* g2buf  = (float*)alloc((size_t)GG * 512 * 4);
    float* mlpPart = (float*)alloc((size_t)8 * 64 * 512 * 4);
    float* part   = (float*)X0;   // pool partials alias X0 (dead after layer 0); 2 MB

    const int* esrc = ei;
    const int* edst = ei + EE;

    // prep; degree hist; parallel degree-sort (scan folded into scatter);
    // pDeg scan; direct permuted-CSR edge scatter.
    prep_all_kernel<<<4649, 256, 0, stream>>>(w_root0, w_rel0, WT0, w_root, w_rel, WTs, x, X0, counts);
    hist_kernel<<<2048, 256, 0, stream>>>(edst, counts);
    deg_hist_kernel<<<128, 256, 0, stream>>>(counts, degHist);
    deg_scatter_kernel<<<128, 256, 0, stream>>>(counts, degHist, degBump, perm, pDeg, iperm);
    scan_kernel<<<1, 1024, 0, stream>>>(pDeg, pRowStart, pCursor);
    scatter_kernel<<<2048, 256, 0, stream>>>(esrc, edst, iperm, pCursor, pssrc);

    // layer 0: F=32 -> H  (permuted CSR). Grid (256,4): N=512 = 4 bn-blocks.
    agg_kernel<<<512, 256, 0, stream>>>(X0, X0 + 32, pRowStart, pssrc, perm);
    gemm_bias_tanh<<<dim3(256, 4), 256, 0, stream>>>(X0, 64, 64, WT0, b0, Xa, 1024);

    // layers 1..4: gemm256 v3 (2-phase minimal template, 16 barriers/block)
    agg_slice_kernel<<<4096, 256, 0, stream>>>(Xa, Xa + 512, pRowStart, pssrc, perm);
    gemm256_bias_tanh<<<256, 512, 0, stream>>>(Xa, 1024, 1024, WTs + 0 * 524288, bvec + 0, Xb, 1024);
    agg_slice_kernel<<<4096, 256, 0, stream>>>(Xb, Xb + 512, pRowStart, pssrc, perm);
    gemm256_bias_tanh<<<256, 512, 0, stream>>>(Xb, 1024, 1024, WTs + 1 * 524288, bvec + 512, Xa, 1024);
    agg_slice_kernel<<<4096, 256, 0, stream>>>(Xa, Xa + 512, pRowStart, pssrc, perm);
    gemm256_bias_tanh<<<256, 512, 0, stream>>>(Xa, 1024, 1024, WTs + 2 * 524288, bvec + 1024, Xb, 1024);
    agg_slice_kernel<<<4096, 256, 0, stream>>>(Xb, Xb + 512, pRowStart, pssrc, perm);
    gemm256_bias_tanh<<<256, 512, 0, stream>>>(Xb, 1024, 1024, WTs + 3 * 524288, bvec + 1536, Xa, 1024);

    // pooling + MLP tail (LDS-staged split-K GEMMs)
    pool_partial<<<dim3(GG, 8), 256, 0, stream>>>(Xa, batch, part);
    pool_combine<<<GG, 256, 0, stream>>>(part, batch, gbufT);
    mlp_splitk<<<dim3(8, 8), 256, 0, stream>>>(gbufT, lin1_w, 512, mlpPart);
    mlp_combine<<<128, 256, 0, stream>>>(mlpPart, 8, lin1_b, 512, nullptr, g1T);
    mlp_splitk<<<dim3(8, 4), 256, 0, stream>>>(g1T, lin2_w, 512, mlpPart);
    mlp_combine<<<128, 256, 0, stream>>>(mlpPart, 4, lin2_b, 512, g2buf, nullptr);
    head_kernel<<<GG, 64, 0, stream>>>(g2buf, lin3_w, lin3_b, out);
}